// Round 3
// baseline (1326.127 us; speedup 1.0000x reference)
//
#include <hip/hip_runtime.h>
#include <hip/hip_bf16.h>

typedef __hip_bfloat16 bf16;

__device__ __forceinline__ float ld(const float* p, size_t i) { return p[i]; }
__device__ __forceinline__ float ld(const bf16* p, size_t i) { return __bfloat162float(p[i]); }

// ---------------- CSR build ----------------
__global__ void init_counts_kernel(int* counts, int n) {
    int i = blockIdx.x * blockDim.x + threadIdx.x;
    if (i < n) counts[i] = 1;  // one self-loop per node
}

__global__ void hist_kernel(const int* __restrict__ dst, int* counts, int E, int n) {
    int i = blockIdx.x * blockDim.x + threadIdx.x;
    if (i < E) {
        int d = dst[i];
        if ((unsigned)d < (unsigned)n) atomicAdd(&counts[d], 1);
    }
}

// single-block exclusive scan; counts -> row_ptr, counts becomes cursor (start offsets)
__global__ void scan_kernel(int* counts, int* row_ptr, int n) {
    __shared__ int wsum[16];
    __shared__ int woff[16];
    int tid = threadIdx.x;
    int lane = tid & 63;
    int wid = tid >> 6;
    int base = 0;
    for (int off = 0; off < n; off += 1024) {
        int i = off + tid;
        int v = (i < n) ? counts[i] : 0;
        int incl = v;
        #pragma unroll
        for (int d = 1; d < 64; d <<= 1) {
            int t = __shfl_up(incl, d, 64);
            if (lane >= d) incl += t;
        }
        if (lane == 63) wsum[wid] = incl;
        __syncthreads();
        if (wid == 0) {
            int wv = (lane < 16) ? wsum[lane] : 0;
            int wincl = wv;
            #pragma unroll
            for (int d = 1; d < 16; d <<= 1) {
                int t = __shfl_up(wincl, d, 64);
                if (lane >= d) wincl += t;
            }
            if (lane < 16) woff[lane] = wincl - wv;
        }
        __syncthreads();
        int chunk_total = woff[15] + wsum[15];
        if (i < n) {
            int excl = base + woff[wid] + incl - v;
            row_ptr[i] = excl;
            counts[i] = excl;  // cursor
        }
        base += chunk_total;
        __syncthreads();
    }
    if (tid == 0) row_ptr[n] = base;
}

__global__ void scatter_kernel(const int* __restrict__ src, const int* __restrict__ dst,
                               int* cursor, int* col_src, int E, int n) {
    int i = blockIdx.x * blockDim.x + threadIdx.x;
    if (i < E) {
        int d = dst[i];
        if ((unsigned)d >= (unsigned)n) return;  // mirror hist drop
        int s = src[i];
        if ((unsigned)s >= (unsigned)n) s = d;   // clamp (shouldn't happen)
        int pos = atomicAdd(&cursor[d], 1);
        col_src[pos] = s;
    } else if (i < E + n) {
        int v = i - E;
        int pos = atomicAdd(&cursor[v], 1);
        col_src[pos] = v;  // self-loop
    }
}

// ---------------- GEMM: C[M,N] = A[M,K] @ B[K,N], fp32 accum ----------------
// TILE_M=64, TILE_N=64, BK=32, block=256, 4x4 micro-tile per thread
template<typename TA>
__global__ __launch_bounds__(256) void gemm_kernel(
        const TA* __restrict__ A, const float* __restrict__ B,
        float* __restrict__ C, int M, int K, int N) {
    __shared__ float As[32][65];  // [k][m], pad to kill bank conflicts
    __shared__ float Bs[32][64];  // [k][n]
    int tid = threadIdx.x;
    int m0 = blockIdx.x * 64;
    int n0 = blockIdx.y * 64;
    int tx = tid & 15, ty = tid >> 4;
    float acc[4][4] = {};
    for (int kt = 0; kt < K; kt += 32) {
        #pragma unroll
        for (int l = 0; l < 8; ++l) {
            int flat = tid + l * 256;         // 0..2047
            int ar = flat >> 5;               // A: 64 rows x 32 cols
            int ac = flat & 31;
            int m = m0 + ar;
            As[ac][ar] = (m < M) ? ld(A, (size_t)m * K + kt + ac) : 0.f;
            int br = flat >> 6;               // B: 32 rows x 64 cols
            int bc = flat & 63;
            Bs[br][bc] = B[(size_t)(kt + br) * N + n0 + bc];
        }
        __syncthreads();
        #pragma unroll
        for (int k = 0; k < 32; ++k) {
            float a[4], b[4];
            #pragma unroll
            for (int i = 0; i < 4; ++i) a[i] = As[k][ty + 16 * i];
            #pragma unroll
            for (int j = 0; j < 4; ++j) b[j] = Bs[k][tx + 16 * j];
            #pragma unroll
            for (int i = 0; i < 4; ++i)
                #pragma unroll
                for (int j = 0; j < 4; ++j) acc[i][j] += a[i] * b[j];
        }
        __syncthreads();
    }
    #pragma unroll
    for (int i = 0; i < 4; ++i) {
        int m = m0 + ty + 16 * i;
        if (m < M) {
            #pragma unroll
            for (int j = 0; j < 4; ++j)
                C[(size_t)m * N + n0 + tx + 16 * j] = acc[i][j];
        }
    }
}

// ---------------- attention logits: as[n,h] = <h[n,h,:], a_src[h,:]> ----------------
template<int H>
__global__ __launch_bounds__(256) void alpha_kernel(
        const float* __restrict__ hbuf, const float* __restrict__ a_src,
        const float* __restrict__ a_dst, float* __restrict__ as,
        float* __restrict__ ad, int n) {
    const int CTOT = H * 64;
    int lane = threadIdx.x & 63;
    int node = blockIdx.x * 4 + (threadIdx.x >> 6);
    if (node >= n) return;
    #pragma unroll
    for (int h = 0; h < H; ++h) {
        float v = hbuf[(size_t)node * CTOT + h * 64 + lane];
        float ps = v * a_src[h * 64 + lane];
        float pd = v * a_dst[h * 64 + lane];
        #pragma unroll
        for (int d = 32; d >= 1; d >>= 1) {
            ps += __shfl_xor(ps, d, 64);
            pd += __shfl_xor(pd, d, 64);
        }
        if (lane == 0) {
            as[(size_t)node * H + h] = ps;
            ad[(size_t)node * H + h] = pd;
        }
    }
}

// ---------------- edge softmax + aggregation (atomic-free, CSR by dst) ----------------
// one block per dst node; thread = channel; head = tid/64
// OUT is float (final layer) or bf16 (intermediate, halves ws footprint)
template<int CTOT, int H, typename TOUT>
__global__ void agg_kernel(const float* __restrict__ hbuf,
                           const float* __restrict__ as, const float* __restrict__ ad,
                           const int* __restrict__ row_ptr, const int* __restrict__ col_src,
                           const float* __restrict__ bias,
                           TOUT* __restrict__ outp, int n, int apply_elu) {
    int node = blockIdx.x;
    int tid = threadIdx.x;
    const int head = tid >> 6;
    int start = row_ptr[node], end = row_ptr[node + 1];
    float adn = ad[(size_t)node * H + head];
    // pass 1: softmax denominator (logits bounded; clamp makes exp overflow impossible)
    float denom = 0.f;
    for (int e = start; e < end; ++e) {
        int s = col_src[e];
        if ((unsigned)s >= (unsigned)n) s = node;   // defensive clamp
        float x = as[(size_t)s * H + head] + adn;
        x = (x > 0.f) ? x : 0.2f * x;               // leaky_relu 0.2
        x = fminf(x, 30.f);
        denom += __expf(x);
    }
    float inv = 1.f / (denom + 1e-16f);
    // pass 2: weighted accumulate
    float acc = 0.f;
    for (int e = start; e < end; ++e) {
        int s = col_src[e];
        if ((unsigned)s >= (unsigned)n) s = node;
        float x = as[(size_t)s * H + head] + adn;
        x = (x > 0.f) ? x : 0.2f * x;
        x = fminf(x, 30.f);
        acc += __expf(x) * inv * hbuf[(size_t)s * CTOT + tid];
    }
    float o = acc + bias[tid];
    if (apply_elu) o = (o > 0.f) ? o : (__expf(o) - 1.f);  // ELU alpha=1
    outp[(size_t)node * CTOT + tid] = (TOUT)o;
}

extern "C" void kernel_launch(void* const* d_in, const int* in_sizes, int n_in,
                              void* d_out, int out_size, void* d_ws, size_t ws_size,
                              hipStream_t stream) {
    const float* x   = (const float*)d_in[0];
    const int*   ei  = (const int*)d_in[1];
    const float* W0  = (const float*)d_in[2];
    const float* as0 = (const float*)d_in[3];
    const float* ad0 = (const float*)d_in[4];
    const float* b0  = (const float*)d_in[5];
    const float* W1  = (const float*)d_in[6];
    const float* as1 = (const float*)d_in[7];
    const float* ad1 = (const float*)d_in[8];
    const float* b1  = (const float*)d_in[9];
    const float* W2  = (const float*)d_in[10];
    const float* as2 = (const float*)d_in[11];
    const float* ad2 = (const float*)d_in[12];
    const float* b2  = (const float*)d_in[13];
    float* out = (float*)d_out;

    const int n = in_sizes[0] / 128;   // 50000
    const int E = in_sizes[1] / 2;     // 800000
    const int* esrc = ei;
    const int* edst = ei + E;

    // workspace layout (~82 MB): hb0 fp32 (gemm out / attention in), hbB bf16 (agg out / gemm in)
    char* ws = (char*)d_ws;
    float* hb0 = (float*)ws;                                 // n*256 fp32  (51.2 MB)
    bf16*  hbB = (bf16*)(ws + (size_t)n * 256 * 4);          // n*256 bf16  (25.6 MB)
    float* asb = (float*)((char*)hbB + (size_t)n * 256 * 2); // n*4 fp32
    float* adb = asb + (size_t)n * 4;                        // n*4 fp32
    int* row_ptr = (int*)(adb + (size_t)n * 4);              // n+1 (+pad)
    int* cursor  = row_ptr + (n + 64);                       // n
    int* col_src = cursor + n;                               // E+n

    // ---- CSR build ----
    init_counts_kernel<<<(n + 255) / 256, 256, 0, stream>>>(cursor, n);
    hist_kernel<<<(E + 255) / 256, 256, 0, stream>>>(edst, cursor, E, n);
    scan_kernel<<<1, 1024, 0, stream>>>(cursor, row_ptr, n);
    scatter_kernel<<<(E + n + 255) / 256, 256, 0, stream>>>(esrc, edst, cursor, col_src, E, n);

    dim3 blk(256);
    // ---- layer 0: x[n,128] @ W0[128,256] ----
    {
        dim3 grid((n + 63) / 64, 4);
        gemm_kernel<float><<<grid, blk, 0, stream>>>(x, W0, hb0, n, 128, 256);
        alpha_kernel<4><<<(n + 3) / 4, blk, 0, stream>>>(hb0, as0, ad0, asb, adb, n);
        agg_kernel<256, 4, bf16><<<n, 256, 0, stream>>>(hb0, asb, adb, row_ptr, col_src, b0,
                                                        hbB, n, 1);
    }
    // ---- layer 1: h[n,256] @ W1[256,256] ----
    {
        dim3 grid((n + 63) / 64, 4);
        gemm_kernel<bf16><<<grid, blk, 0, stream>>>(hbB, W1, hb0, n, 256, 256);
        alpha_kernel<4><<<(n + 3) / 4, blk, 0, stream>>>(hb0, as1, ad1, asb, adb, n);
        agg_kernel<256, 4, bf16><<<n, 256, 0, stream>>>(hb0, asb, adb, row_ptr, col_src, b1,
                                                        hbB, n, 1);
    }
    // ---- layer 2: h[n,256] @ W2[256,64], heads=1, no ELU, fp32 out ----
    {
        dim3 grid((n + 63) / 64, 1);
        gemm_kernel<bf16><<<grid, blk, 0, stream>>>(hbB, W2, hb0, n, 256, 64);
        alpha_kernel<1><<<(n + 3) / 4, blk, 0, stream>>>(hb0, as2, ad2, asb, adb, n);
        agg_kernel<64, 1, float><<<n, 64, 0, stream>>>(hb0, asb, adb, row_ptr, col_src, b2,
                                                       out, n, 0);
    }
}

// Round 4
// 865.974 us; speedup vs baseline: 1.5314x; 1.5314x over previous
//
#include <hip/hip_runtime.h>
#include <hip/hip_bf16.h>

typedef __hip_bfloat16 bf16;

__device__ __forceinline__ float ld(const float* p, size_t i) { return p[i]; }
__device__ __forceinline__ float ld(const bf16* p, size_t i) { return __bfloat162float(p[i]); }

// ---------------- CSR build ----------------
__global__ void init_counts_kernel(int* counts, int n) {
    int i = blockIdx.x * blockDim.x + threadIdx.x;
    if (i < n) counts[i] = 1;  // one self-loop per node
}

__global__ void hist_kernel(const int* __restrict__ dst, int* counts, int E, int n) {
    int i = blockIdx.x * blockDim.x + threadIdx.x;
    if (i < E) {
        int d = dst[i];
        if ((unsigned)d < (unsigned)n) atomicAdd(&counts[d], 1);
    }
}

// single-block exclusive scan; counts -> row_ptr, counts becomes cursor (start offsets)
__global__ void scan_kernel(int* counts, int* row_ptr, int n) {
    __shared__ int wsum[16];
    __shared__ int woff[16];
    int tid = threadIdx.x;
    int lane = tid & 63;
    int wid = tid >> 6;
    int base = 0;
    for (int off = 0; off < n; off += 1024) {
        int i = off + tid;
        int v = (i < n) ? counts[i] : 0;
        int incl = v;
        #pragma unroll
        for (int d = 1; d < 64; d <<= 1) {
            int t = __shfl_up(incl, d, 64);
            if (lane >= d) incl += t;
        }
        if (lane == 63) wsum[wid] = incl;
        __syncthreads();
        if (wid == 0) {
            int wv = (lane < 16) ? wsum[lane] : 0;
            int wincl = wv;
            #pragma unroll
            for (int d = 1; d < 16; d <<= 1) {
                int t = __shfl_up(wincl, d, 64);
                if (lane >= d) wincl += t;
            }
            if (lane < 16) woff[lane] = wincl - wv;
        }
        __syncthreads();
        int chunk_total = woff[15] + wsum[15];
        if (i < n) {
            int excl = base + woff[wid] + incl - v;
            row_ptr[i] = excl;
            counts[i] = excl;  // cursor
        }
        base += chunk_total;
        __syncthreads();
    }
    if (tid == 0) row_ptr[n] = base;
}

__global__ void scatter_kernel(const int* __restrict__ src, const int* __restrict__ dst,
                               int* cursor, int* col_src, int E, int n) {
    int i = blockIdx.x * blockDim.x + threadIdx.x;
    if (i < E) {
        int d = dst[i];
        if ((unsigned)d >= (unsigned)n) return;  // mirror hist drop
        int s = src[i];
        if ((unsigned)s >= (unsigned)n) s = d;   // clamp (shouldn't happen)
        int pos = atomicAdd(&cursor[d], 1);
        col_src[pos] = s;
    } else if (i < E + n) {
        int v = i - E;
        int pos = atomicAdd(&cursor[v], 1);
        col_src[pos] = v;  // self-loop
    }
}

// ---------------- GEMM: C[M,N] = A[M,K] @ B[K,N], fp32 accum, bf16 out ----------------
// TILE_M=64, TILE_N=64, BK=32, block=256, 4x4 micro-tile per thread
template<typename TA>
__global__ __launch_bounds__(256) void gemm_kernel(
        const TA* __restrict__ A, const float* __restrict__ B,
        bf16* __restrict__ C, int M, int K, int N) {
    __shared__ float As[32][65];  // [k][m], pad to kill bank conflicts
    __shared__ float Bs[32][64];  // [k][n]
    int tid = threadIdx.x;
    int m0 = blockIdx.x * 64;
    int n0 = blockIdx.y * 64;
    int tx = tid & 15, ty = tid >> 4;
    float acc[4][4] = {};
    for (int kt = 0; kt < K; kt += 32) {
        #pragma unroll
        for (int l = 0; l < 8; ++l) {
            int flat = tid + l * 256;         // 0..2047
            int ar = flat >> 5;               // A: 64 rows x 32 cols
            int ac = flat & 31;
            int m = m0 + ar;
            As[ac][ar] = (m < M) ? ld(A, (size_t)m * K + kt + ac) : 0.f;
            int br = flat >> 6;               // B: 32 rows x 64 cols
            int bc = flat & 63;
            Bs[br][bc] = B[(size_t)(kt + br) * N + n0 + bc];
        }
        __syncthreads();
        #pragma unroll
        for (int k = 0; k < 32; ++k) {
            float a[4], b[4];
            #pragma unroll
            for (int i = 0; i < 4; ++i) a[i] = As[k][ty + 16 * i];
            #pragma unroll
            for (int j = 0; j < 4; ++j) b[j] = Bs[k][tx + 16 * j];
            #pragma unroll
            for (int i = 0; i < 4; ++i)
                #pragma unroll
                for (int j = 0; j < 4; ++j) acc[i][j] += a[i] * b[j];
        }
        __syncthreads();
    }
    #pragma unroll
    for (int i = 0; i < 4; ++i) {
        int m = m0 + ty + 16 * i;
        if (m < M) {
            #pragma unroll
            for (int j = 0; j < 4; ++j)
                C[(size_t)m * N + n0 + tx + 16 * j] = (bf16)acc[i][j];
        }
    }
}

// ---------------- attention logits: as[n,h] = <h[n,h,:], a_src[h,:]> ----------------
template<int H>
__global__ __launch_bounds__(256) void alpha_kernel(
        const bf16* __restrict__ hbuf, const float* __restrict__ a_src,
        const float* __restrict__ a_dst, float* __restrict__ as,
        float* __restrict__ ad, int n) {
    const int CTOT = H * 64;
    int lane = threadIdx.x & 63;
    int node = blockIdx.x * 4 + (threadIdx.x >> 6);
    if (node >= n) return;
    #pragma unroll
    for (int h = 0; h < H; ++h) {
        float v = __bfloat162float(hbuf[(size_t)node * CTOT + h * 64 + lane]);
        float ps = v * a_src[h * 64 + lane];
        float pd = v * a_dst[h * 64 + lane];
        #pragma unroll
        for (int d = 32; d >= 1; d >>= 1) {
            ps += __shfl_xor(ps, d, 64);
            pd += __shfl_xor(pd, d, 64);
        }
        if (lane == 0) {
            as[(size_t)node * H + h] = ps;
            ad[(size_t)node * H + h] = pd;
        }
    }
}

// ---------------- edge softmax + aggregation, SINGLE PASS (atomic-free, CSR by dst) ----
// out = (sum_i w_i * h_i) / (sum_i w_i);  w_i = exp(leaky_relu(as[src]+ad[dst]))
// one block per dst node; thread = channel; head = tid/64; 2-edge unroll for MLP
template<int CTOT, int H, typename TOUT>
__global__ void agg_kernel(const bf16* __restrict__ hbuf,
                           const float* __restrict__ as, const float* __restrict__ ad,
                           const int* __restrict__ row_ptr, const int* __restrict__ col_src,
                           const float* __restrict__ bias,
                           TOUT* __restrict__ outp, int n, int apply_elu) {
    int node = blockIdx.x;
    int tid = threadIdx.x;
    const int head = tid >> 6;
    int start = row_ptr[node], end = row_ptr[node + 1];
    float adn = ad[(size_t)node * H + head];
    float denom = 0.f, acc = 0.f;
    int e = start;
    for (; e + 2 <= end; e += 2) {
        int s0 = col_src[e], s1 = col_src[e + 1];
        if ((unsigned)s0 >= (unsigned)n) s0 = node;
        if ((unsigned)s1 >= (unsigned)n) s1 = node;
        float x0 = as[(size_t)s0 * H + head] + adn;
        float x1 = as[(size_t)s1 * H + head] + adn;
        float h0 = __bfloat162float(hbuf[(size_t)s0 * CTOT + tid]);
        float h1 = __bfloat162float(hbuf[(size_t)s1 * CTOT + tid]);
        x0 = (x0 > 0.f) ? x0 : 0.2f * x0;  x0 = fminf(x0, 30.f);
        x1 = (x1 > 0.f) ? x1 : 0.2f * x1;  x1 = fminf(x1, 30.f);
        float w0 = __expf(x0), w1 = __expf(x1);
        denom += w0 + w1;
        acc += w0 * h0 + w1 * h1;
    }
    if (e < end) {
        int s = col_src[e];
        if ((unsigned)s >= (unsigned)n) s = node;
        float x = as[(size_t)s * H + head] + adn;
        x = (x > 0.f) ? x : 0.2f * x;  x = fminf(x, 30.f);
        float w = __expf(x);
        denom += w;
        acc += w * __bfloat162float(hbuf[(size_t)s * CTOT + tid]);
    }
    float o = acc / (denom + 1e-16f) + bias[tid];
    if (apply_elu) o = (o > 0.f) ? o : (__expf(o) - 1.f);  // ELU alpha=1
    outp[(size_t)node * CTOT + tid] = (TOUT)o;
}

extern "C" void kernel_launch(void* const* d_in, const int* in_sizes, int n_in,
                              void* d_out, int out_size, void* d_ws, size_t ws_size,
                              hipStream_t stream) {
    const float* x   = (const float*)d_in[0];
    const int*   ei  = (const int*)d_in[1];
    const float* W0  = (const float*)d_in[2];
    const float* as0 = (const float*)d_in[3];
    const float* ad0 = (const float*)d_in[4];
    const float* b0  = (const float*)d_in[5];
    const float* W1  = (const float*)d_in[6];
    const float* as1 = (const float*)d_in[7];
    const float* ad1 = (const float*)d_in[8];
    const float* b1  = (const float*)d_in[9];
    const float* W2  = (const float*)d_in[10];
    const float* as2 = (const float*)d_in[11];
    const float* ad2 = (const float*)d_in[12];
    const float* b2  = (const float*)d_in[13];
    float* out = (float*)d_out;

    const int n = in_sizes[0] / 128;   // 50000
    const int E = in_sizes[1] / 2;     // 800000
    const int* esrc = ei;
    const int* edst = ei + E;

    // workspace (~56 MB): two bf16 h-buffers + logits + CSR
    char* ws = (char*)d_ws;
    bf16* hb0 = (bf16*)ws;                                   // n*256 bf16 (25.6 MB)
    bf16* hb1 = hb0 + (size_t)n * 256;                       // n*256 bf16 (25.6 MB)
    float* asb = (float*)(hb1 + (size_t)n * 256);            // n*4 fp32
    float* adb = asb + (size_t)n * 4;                        // n*4 fp32
    int* row_ptr = (int*)(adb + (size_t)n * 4);              // n+1 (+pad)
    int* cursor  = row_ptr + (n + 64);                       // n
    int* col_src = cursor + n;                               // E+n

    // ---- CSR build ----
    init_counts_kernel<<<(n + 255) / 256, 256, 0, stream>>>(cursor, n);
    hist_kernel<<<(E + 255) / 256, 256, 0, stream>>>(edst, cursor, E, n);
    scan_kernel<<<1, 1024, 0, stream>>>(cursor, row_ptr, n);
    scatter_kernel<<<(E + n + 255) / 256, 256, 0, stream>>>(esrc, edst, cursor, col_src, E, n);

    dim3 blk(256);
    // ---- layer 0: x[n,128] @ W0[128,256] ----
    {
        dim3 grid((n + 63) / 64, 4);
        gemm_kernel<float><<<grid, blk, 0, stream>>>(x, W0, hb0, n, 128, 256);
        alpha_kernel<4><<<(n + 3) / 4, blk, 0, stream>>>(hb0, as0, ad0, asb, adb, n);
        agg_kernel<256, 4, bf16><<<n, 256, 0, stream>>>(hb0, asb, adb, row_ptr, col_src, b0,
                                                        hb1, n, 1);
    }
    // ---- layer 1: h[n,256] @ W1[256,256] ----
    {
        dim3 grid((n + 63) / 64, 4);
        gemm_kernel<bf16><<<grid, blk, 0, stream>>>(hb1, W1, hb0, n, 256, 256);
        alpha_kernel<4><<<(n + 3) / 4, blk, 0, stream>>>(hb0, as1, ad1, asb, adb, n);
        agg_kernel<256, 4, bf16><<<n, 256, 0, stream>>>(hb0, asb, adb, row_ptr, col_src, b1,
                                                        hb1, n, 1);
    }
    // ---- layer 2: h[n,256] @ W2[256,64], heads=1, no ELU, fp32 out ----
    {
        dim3 grid((n + 63) / 64, 1);
        gemm_kernel<bf16><<<grid, blk, 0, stream>>>(hb1, W2, hb0, n, 256, 64);
        alpha_kernel<1><<<(n + 3) / 4, blk, 0, stream>>>(hb0, as2, ad2, asb, adb, n);
        agg_kernel<64, 1, float><<<n, 64, 0, stream>>>(hb0, asb, adb, row_ptr, col_src, b2,
                                                       out, n, 0);
    }
}

// Round 5
// 644.837 us; speedup vs baseline: 2.0565x; 1.3429x over previous
//
#include <hip/hip_runtime.h>
#include <hip/hip_bf16.h>

typedef __hip_bfloat16 bf16;
typedef short s8v __attribute__((ext_vector_type(8)));   // 8 bf16 (4 VGPRs)
typedef float f32x4 __attribute__((ext_vector_type(4))); // MFMA accumulator

__device__ __forceinline__ unsigned short f2bf_bits(float x) {
    union { bf16 h; unsigned short u; } v; v.h = __float2bfloat16(x); return v.u;
}

// load 8 elements as bf16 bit-pattern (16B)
__device__ __forceinline__ uint4 load8(const bf16* p) {
    return *(const uint4*)p;
}
__device__ __forceinline__ uint4 load8(const float* p) {
    const float4* q = (const float4*)p;
    float4 f0 = q[0], f1 = q[1];
    unsigned short u[8];
    u[0] = f2bf_bits(f0.x); u[1] = f2bf_bits(f0.y); u[2] = f2bf_bits(f0.z); u[3] = f2bf_bits(f0.w);
    u[4] = f2bf_bits(f1.x); u[5] = f2bf_bits(f1.y); u[6] = f2bf_bits(f1.z); u[7] = f2bf_bits(f1.w);
    return *(uint4*)u;
}

// ---------------- CSR build ----------------
__global__ void init_counts_kernel(int* counts, int n) {
    int i = blockIdx.x * blockDim.x + threadIdx.x;
    if (i < n) counts[i] = 1;  // one self-loop per node
}

__global__ void hist_kernel(const int* __restrict__ dst, int* counts, int E, int n) {
    int i = blockIdx.x * blockDim.x + threadIdx.x;
    if (i < E) {
        int d = dst[i];
        if ((unsigned)d < (unsigned)n) atomicAdd(&counts[d], 1);
    }
}

// single-block exclusive scan; counts -> row_ptr, counts becomes cursor (start offsets)
__global__ void scan_kernel(int* counts, int* row_ptr, int n) {
    __shared__ int wsum[16];
    __shared__ int woff[16];
    int tid = threadIdx.x;
    int lane = tid & 63;
    int wid = tid >> 6;
    int base = 0;
    for (int off = 0; off < n; off += 1024) {
        int i = off + tid;
        int v = (i < n) ? counts[i] : 0;
        int incl = v;
        #pragma unroll
        for (int d = 1; d < 64; d <<= 1) {
            int t = __shfl_up(incl, d, 64);
            if (lane >= d) incl += t;
        }
        if (lane == 63) wsum[wid] = incl;
        __syncthreads();
        if (wid == 0) {
            int wv = (lane < 16) ? wsum[lane] : 0;
            int wincl = wv;
            #pragma unroll
            for (int d = 1; d < 16; d <<= 1) {
                int t = __shfl_up(wincl, d, 64);
                if (lane >= d) wincl += t;
            }
            if (lane < 16) woff[lane] = wincl - wv;
        }
        __syncthreads();
        int chunk_total = woff[15] + wsum[15];
        if (i < n) {
            int excl = base + woff[wid] + incl - v;
            row_ptr[i] = excl;
            counts[i] = excl;  // cursor
        }
        base += chunk_total;
        __syncthreads();
    }
    if (tid == 0) row_ptr[n] = base;
}

__global__ void scatter_kernel(const int* __restrict__ src, const int* __restrict__ dst,
                               int* cursor, int* col_src, int E, int n) {
    int i = blockIdx.x * blockDim.x + threadIdx.x;
    if (i < E) {
        int d = dst[i];
        if ((unsigned)d >= (unsigned)n) return;
        int s = src[i];
        if ((unsigned)s >= (unsigned)n) s = d;
        int pos = atomicAdd(&cursor[d], 1);
        col_src[pos] = s;
    } else if (i < E + n) {
        int v = i - E;
        int pos = atomicAdd(&cursor[v], 1);
        col_src[pos] = v;  // self-loop
    }
}

// ---------------- W[k][n] fp32 -> Wt[n][k] bf16 (one-time, L2-resident) ----------------
__global__ void transpose_kernel(const float* __restrict__ W, bf16* __restrict__ Wt,
                                 int K, int N) {
    int idx = blockIdx.x * blockDim.x + threadIdx.x;
    if (idx >= K * N) return;
    int nn = idx / K, k = idx - nn * K;
    Wt[idx] = __float2bfloat16(W[(size_t)k * N + nn]);
}

// ---------------- MFMA GEMM: C[M,N] = A[M,K] @ W[K,N], bf16 in, fp32 acc, bf16 out ----
// Wt is W transposed [n][k] bf16. Tile 64x64, BK=64, 4 waves, wave = 16-row strip.
template<typename TA>
__global__ __launch_bounds__(256) void mfma_gemm_kernel(
        const TA* __restrict__ A, const bf16* __restrict__ Wt,
        bf16* __restrict__ C, int M, int K, int N) {
    __shared__ __align__(16) bf16 As[64][72];  // 144B row stride = 9x16B -> <=2-way banks
    __shared__ __align__(16) bf16 Bs[64][72];
    int tid = threadIdx.x;
    int m0 = blockIdx.x * 64;
    int n0 = blockIdx.y * 64;
    int w = tid >> 6;          // wave 0..3 -> M-strip
    int l = tid & 63;
    int lm = l & 15;
    int quad = l >> 4;
    int r = tid >> 2;          // staging row 0..63
    int kb = (tid & 3) * 8;    // staging k-offset {0,8,16,24}
    f32x4 acc[4] = {};
    int mstage = m0 + r;
    for (int kt = 0; kt < K; kt += 64) {
        #pragma unroll
        for (int c = 0; c < 2; ++c) {
            int kk = kb + c * 32;
            uint4 av = (mstage < M) ? load8(&A[(size_t)mstage * K + kt + kk])
                                    : make_uint4(0, 0, 0, 0);
            *(uint4*)&As[r][kk] = av;
            *(uint4*)&Bs[r][kk] = load8(&Wt[(size_t)(n0 + r) * K + kt + kk]);
        }
        __syncthreads();
        #pragma unroll
        for (int ks = 0; ks < 2; ++ks) {
            s8v a = *(const s8v*)&As[w * 16 + lm][ks * 32 + quad * 8];
            #pragma unroll
            for (int nb = 0; nb < 4; ++nb) {
                s8v b = *(const s8v*)&Bs[nb * 16 + lm][ks * 32 + quad * 8];
                acc[nb] = __builtin_amdgcn_mfma_f32_16x16x32_bf16(a, b, acc[nb], 0, 0, 0);
            }
        }
        __syncthreads();
    }
    // C/D layout: col = lane&15, row = quad*4 + reg
    #pragma unroll
    for (int nb = 0; nb < 4; ++nb) {
        #pragma unroll
        for (int reg = 0; reg < 4; ++reg) {
            int m = m0 + w * 16 + quad * 4 + reg;
            if (m < M)
                C[(size_t)m * N + n0 + nb * 16 + lm] = __float2bfloat16(acc[nb][reg]);
        }
    }
}

// ---------------- attention logits: as[n,h] = <h[n,h,:], a_src[h,:]> ----------------
template<int H>
__global__ __launch_bounds__(256) void alpha_kernel(
        const bf16* __restrict__ hbuf, const float* __restrict__ a_src,
        const float* __restrict__ a_dst, float* __restrict__ as,
        float* __restrict__ ad, int n) {
    const int CTOT = H * 64;
    int lane = threadIdx.x & 63;
    int node = blockIdx.x * 4 + (threadIdx.x >> 6);
    if (node >= n) return;
    #pragma unroll
    for (int h = 0; h < H; ++h) {
        float v = __bfloat162float(hbuf[(size_t)node * CTOT + h * 64 + lane]);
        float ps = v * a_src[h * 64 + lane];
        float pd = v * a_dst[h * 64 + lane];
        #pragma unroll
        for (int d = 32; d >= 1; d >>= 1) {
            ps += __shfl_xor(ps, d, 64);
            pd += __shfl_xor(pd, d, 64);
        }
        if (lane == 0) {
            as[(size_t)node * H + h] = ps;
            ad[(size_t)node * H + h] = pd;
        }
    }
}

// ---------------- edge softmax + aggregation, SINGLE PASS (atomic-free, CSR by dst) ----
template<int CTOT, int H, typename TOUT>
__global__ void agg_kernel(const bf16* __restrict__ hbuf,
                           const float* __restrict__ as, const float* __restrict__ ad,
                           const int* __restrict__ row_ptr, const int* __restrict__ col_src,
                           const float* __restrict__ bias,
                           TOUT* __restrict__ outp, int n, int apply_elu) {
    int node = blockIdx.x;
    int tid = threadIdx.x;
    const int head = tid >> 6;
    int start = row_ptr[node], end = row_ptr[node + 1];
    float adn = ad[(size_t)node * H + head];
    float denom = 0.f, acc = 0.f;
    int e = start;
    for (; e + 2 <= end; e += 2) {
        int s0 = col_src[e], s1 = col_src[e + 1];
        if ((unsigned)s0 >= (unsigned)n) s0 = node;
        if ((unsigned)s1 >= (unsigned)n) s1 = node;
        float x0 = as[(size_t)s0 * H + head] + adn;
        float x1 = as[(size_t)s1 * H + head] + adn;
        float h0 = __bfloat162float(hbuf[(size_t)s0 * CTOT + tid]);
        float h1 = __bfloat162float(hbuf[(size_t)s1 * CTOT + tid]);
        x0 = (x0 > 0.f) ? x0 : 0.2f * x0;  x0 = fminf(x0, 30.f);
        x1 = (x1 > 0.f) ? x1 : 0.2f * x1;  x1 = fminf(x1, 30.f);
        float w0 = __expf(x0), w1 = __expf(x1);
        denom += w0 + w1;
        acc += w0 * h0 + w1 * h1;
    }
    if (e < end) {
        int s = col_src[e];
        if ((unsigned)s >= (unsigned)n) s = node;
        float x = as[(size_t)s * H + head] + adn;
        x = (x > 0.f) ? x : 0.2f * x;  x = fminf(x, 30.f);
        float w = __expf(x);
        denom += w;
        acc += w * __bfloat162float(hbuf[(size_t)s * CTOT + tid]);
    }
    float o = acc / (denom + 1e-16f) + bias[tid];
    if (apply_elu) o = (o > 0.f) ? o : (__expf(o) - 1.f);  // ELU alpha=1
    outp[(size_t)node * CTOT + tid] = (TOUT)o;
}

extern "C" void kernel_launch(void* const* d_in, const int* in_sizes, int n_in,
                              void* d_out, int out_size, void* d_ws, size_t ws_size,
                              hipStream_t stream) {
    const float* x   = (const float*)d_in[0];
    const int*   ei  = (const int*)d_in[1];
    const float* W0  = (const float*)d_in[2];
    const float* as0 = (const float*)d_in[3];
    const float* ad0 = (const float*)d_in[4];
    const float* b0  = (const float*)d_in[5];
    const float* W1  = (const float*)d_in[6];
    const float* as1 = (const float*)d_in[7];
    const float* ad1 = (const float*)d_in[8];
    const float* b1  = (const float*)d_in[9];
    const float* W2  = (const float*)d_in[10];
    const float* as2 = (const float*)d_in[11];
    const float* ad2 = (const float*)d_in[12];
    const float* b2  = (const float*)d_in[13];
    float* out = (float*)d_out;

    const int n = in_sizes[0] / 128;   // 50000
    const int E = in_sizes[1] / 2;     // 800000
    const int* esrc = ei;
    const int* edst = ei + E;

    // workspace (~57 MB)
    char* ws = (char*)d_ws;
    bf16* hb0 = (bf16*)ws;                                   // n*256 bf16
    bf16* hb1 = hb0 + (size_t)n * 256;                       // n*256 bf16
    bf16* wt0 = hb1 + (size_t)n * 256;                       // 256*128
    bf16* wt1 = wt0 + 128 * 256;                             // 256*256
    bf16* wt2 = wt1 + 256 * 256;                             // 64*256
    float* asb = (float*)(wt2 + 256 * 64);                   // n*4 fp32
    float* adb = asb + (size_t)n * 4;                        // n*4 fp32
    int* row_ptr = (int*)(adb + (size_t)n * 4);              // n+1 (+pad)
    int* cursor  = row_ptr + (n + 64);                       // n
    int* col_src = cursor + n;                               // E+n

    // ---- weight transposes (bf16) + CSR build ----
    transpose_kernel<<<(128 * 256 + 255) / 256, 256, 0, stream>>>(W0, wt0, 128, 256);
    transpose_kernel<<<(256 * 256 + 255) / 256, 256, 0, stream>>>(W1, wt1, 256, 256);
    transpose_kernel<<<(256 * 64 + 255) / 256, 256, 0, stream>>>(W2, wt2, 256, 64);
    init_counts_kernel<<<(n + 255) / 256, 256, 0, stream>>>(cursor, n);
    hist_kernel<<<(E + 255) / 256, 256, 0, stream>>>(edst, cursor, E, n);
    scan_kernel<<<1, 1024, 0, stream>>>(cursor, row_ptr, n);
    scatter_kernel<<<(E + n + 255) / 256, 256, 0, stream>>>(esrc, edst, cursor, col_src, E, n);

    dim3 blk(256);
    int mg = (n + 63) / 64;
    // ---- layer 0: x[n,128] @ W0[128,256] ----
    {
        mfma_gemm_kernel<float><<<dim3(mg, 4), blk, 0, stream>>>(x, wt0, hb0, n, 128, 256);
        alpha_kernel<4><<<(n + 3) / 4, blk, 0, stream>>>(hb0, as0, ad0, asb, adb, n);
        agg_kernel<256, 4, bf16><<<n, 256, 0, stream>>>(hb0, asb, adb, row_ptr, col_src, b0,
                                                        hb1, n, 1);
    }
    // ---- layer 1: h[n,256] @ W1[256,256] ----
    {
        mfma_gemm_kernel<bf16><<<dim3(mg, 4), blk, 0, stream>>>(hb1, wt1, hb0, n, 256, 256);
        alpha_kernel<4><<<(n + 3) / 4, blk, 0, stream>>>(hb0, as1, ad1, asb, adb, n);
        agg_kernel<256, 4, bf16><<<n, 256, 0, stream>>>(hb0, asb, adb, row_ptr, col_src, b1,
                                                        hb1, n, 1);
    }
    // ---- layer 2: h[n,256] @ W2[256,64], heads=1, no ELU, fp32 out ----
    {
        mfma_gemm_kernel<bf16><<<dim3(mg, 1), blk, 0, stream>>>(hb1, wt2, hb0, n, 256, 64);
        alpha_kernel<1><<<(n + 3) / 4, blk, 0, stream>>>(hb0, as2, ad2, asb, adb, n);
        agg_kernel<64, 1, float><<<n, 64, 0, stream>>>(hb0, asb, adb, row_ptr, col_src, b2,
                                                       out, n, 0);
    }
}

// Round 6
// 531.175 us; speedup vs baseline: 2.4966x; 1.2140x over previous
//
#include <hip/hip_runtime.h>
#include <hip/hip_bf16.h>

typedef __hip_bfloat16 bf16;
typedef short s8v __attribute__((ext_vector_type(8)));   // 8 bf16 (4 VGPRs)
typedef float f32x4 __attribute__((ext_vector_type(4))); // MFMA accumulator

__device__ __forceinline__ unsigned short f2bf_bits(float x) {
    union { bf16 h; unsigned short u; } v; v.h = __float2bfloat16(x); return v.u;
}
__device__ __forceinline__ float bfbits2f(unsigned short u) {
    union { unsigned u32; float f; } v; v.u32 = ((unsigned)u) << 16; return v.f;
}

// load 8 elements as bf16 bit-pattern (16B)
__device__ __forceinline__ uint4 load8(const bf16* p) {
    return *(const uint4*)p;
}
__device__ __forceinline__ uint4 load8(const float* p) {
    const float4* q = (const float4*)p;
    float4 f0 = q[0], f1 = q[1];
    unsigned short u[8];
    u[0] = f2bf_bits(f0.x); u[1] = f2bf_bits(f0.y); u[2] = f2bf_bits(f0.z); u[3] = f2bf_bits(f0.w);
    u[4] = f2bf_bits(f1.x); u[5] = f2bf_bits(f1.y); u[6] = f2bf_bits(f1.z); u[7] = f2bf_bits(f1.w);
    return *(uint4*)u;
}

// ---------------- CSR build ----------------
__global__ void init_counts_kernel(int* counts, int n) {
    int i = blockIdx.x * blockDim.x + threadIdx.x;
    if (i < n) counts[i] = 1;  // one self-loop per node
}

__global__ void hist_kernel(const int* __restrict__ dst, int* counts, int E, int n) {
    int i = blockIdx.x * blockDim.x + threadIdx.x;
    if (i < E) {
        int d = dst[i];
        if ((unsigned)d < (unsigned)n) atomicAdd(&counts[d], 1);
    }
}

// single-block exclusive scan; counts -> row_ptr, counts becomes cursor (start offsets)
__global__ void scan_kernel(int* counts, int* row_ptr, int n) {
    __shared__ int wsum[16];
    __shared__ int woff[16];
    int tid = threadIdx.x;
    int lane = tid & 63;
    int wid = tid >> 6;
    int base = 0;
    for (int off = 0; off < n; off += 1024) {
        int i = off + tid;
        int v = (i < n) ? counts[i] : 0;
        int incl = v;
        #pragma unroll
        for (int d = 1; d < 64; d <<= 1) {
            int t = __shfl_up(incl, d, 64);
            if (lane >= d) incl += t;
        }
        if (lane == 63) wsum[wid] = incl;
        __syncthreads();
        if (wid == 0) {
            int wv = (lane < 16) ? wsum[lane] : 0;
            int wincl = wv;
            #pragma unroll
            for (int d = 1; d < 16; d <<= 1) {
                int t = __shfl_up(wincl, d, 64);
                if (lane >= d) wincl += t;
            }
            if (lane < 16) woff[lane] = wincl - wv;
        }
        __syncthreads();
        int chunk_total = woff[15] + wsum[15];
        if (i < n) {
            int excl = base + woff[wid] + incl - v;
            row_ptr[i] = excl;
            counts[i] = excl;  // cursor
        }
        base += chunk_total;
        __syncthreads();
    }
    if (tid == 0) row_ptr[n] = base;
}

__global__ void scatter_kernel(const int* __restrict__ src, const int* __restrict__ dst,
                               int* cursor, int* col_src, int E, int n) {
    int i = blockIdx.x * blockDim.x + threadIdx.x;
    if (i < E) {
        int d = dst[i];
        if ((unsigned)d >= (unsigned)n) return;
        int s = src[i];
        if ((unsigned)s >= (unsigned)n) s = d;
        int pos = atomicAdd(&cursor[d], 1);
        col_src[pos] = s;
    } else if (i < E + n) {
        int v = i - E;
        int pos = atomicAdd(&cursor[v], 1);
        col_src[pos] = v;  // self-loop
    }
}

// ---------------- W[k][n] fp32 -> Wt[n][k] bf16 (one-time, L2-resident) ----------------
__global__ void transpose_kernel(const float* __restrict__ W, bf16* __restrict__ Wt,
                                 int K, int N) {
    int idx = blockIdx.x * blockDim.x + threadIdx.x;
    if (idx >= K * N) return;
    int nn = idx / K, k = idx - nn * K;
    Wt[idx] = __float2bfloat16(W[(size_t)k * N + nn]);
}

// ---------------- MFMA GEMM: C[M,N] = A[M,K] @ W[K,N], bf16 in, fp32 acc, bf16 out ----
// Wt is W transposed [n][k] bf16. Tile 64x64, BK=64, 4 waves, wave = 16-row strip.
template<typename TA>
__global__ __launch_bounds__(256) void mfma_gemm_kernel(
        const TA* __restrict__ A, const bf16* __restrict__ Wt,
        bf16* __restrict__ C, int M, int K, int N) {
    __shared__ __align__(16) bf16 As[64][72];  // 144B row stride = 9x16B -> <=2-way banks
    __shared__ __align__(16) bf16 Bs[64][72];
    int tid = threadIdx.x;
    int m0 = blockIdx.x * 64;
    int n0 = blockIdx.y * 64;
    int w = tid >> 6;          // wave 0..3 -> M-strip
    int l = tid & 63;
    int lm = l & 15;
    int quad = l >> 4;
    int r = tid >> 2;          // staging row 0..63
    int kb = (tid & 3) * 8;    // staging k-offset {0,8,16,24}
    f32x4 acc[4] = {};
    int mstage = m0 + r;
    for (int kt = 0; kt < K; kt += 64) {
        #pragma unroll
        for (int c = 0; c < 2; ++c) {
            int kk = kb + c * 32;
            uint4 av = (mstage < M) ? load8(&A[(size_t)mstage * K + kt + kk])
                                    : make_uint4(0, 0, 0, 0);
            *(uint4*)&As[r][kk] = av;
            *(uint4*)&Bs[r][kk] = load8(&Wt[(size_t)(n0 + r) * K + kt + kk]);
        }
        __syncthreads();
        #pragma unroll
        for (int ks = 0; ks < 2; ++ks) {
            s8v a = *(const s8v*)&As[w * 16 + lm][ks * 32 + quad * 8];
            #pragma unroll
            for (int nb = 0; nb < 4; ++nb) {
                s8v b = *(const s8v*)&Bs[nb * 16 + lm][ks * 32 + quad * 8];
                acc[nb] = __builtin_amdgcn_mfma_f32_16x16x32_bf16(a, b, acc[nb], 0, 0, 0);
            }
        }
        __syncthreads();
    }
    // C/D layout: col = lane&15, row = quad*4 + reg
    #pragma unroll
    for (int nb = 0; nb < 4; ++nb) {
        #pragma unroll
        for (int reg = 0; reg < 4; ++reg) {
            int m = m0 + w * 16 + quad * 4 + reg;
            if (m < M)
                C[(size_t)m * N + n0 + nb * 16 + lm] = __float2bfloat16(acc[nb][reg]);
        }
    }
}

// ---------------- attention logits: as[n,h] = <h[n,h,:], a_src[h,:]> ----------------
template<int H>
__global__ __launch_bounds__(256) void alpha_kernel(
        const bf16* __restrict__ hbuf, const float* __restrict__ a_src,
        const float* __restrict__ a_dst, float* __restrict__ as,
        float* __restrict__ ad, int n) {
    const int CTOT = H * 64;
    int lane = threadIdx.x & 63;
    int node = blockIdx.x * 4 + (threadIdx.x >> 6);
    if (node >= n) return;
    #pragma unroll
    for (int h = 0; h < H; ++h) {
        float v = __bfloat162float(hbuf[(size_t)node * CTOT + h * 64 + lane]);
        float ps = v * a_src[h * 64 + lane];
        float pd = v * a_dst[h * 64 + lane];
        #pragma unroll
        for (int d = 32; d >= 1; d >>= 1) {
            ps += __shfl_xor(ps, d, 64);
            pd += __shfl_xor(pd, d, 64);
        }
        if (lane == 0) {
            as[(size_t)node * H + h] = ps;
            ad[(size_t)node * H + h] = pd;
        }
    }
}

// ---------------- edge softmax + aggregation, SINGLE PASS, channel-vectorized --------
// One WAVE per dst node; lane owns VEC consecutive channels (VEC*64 == CTOT).
// out = (sum_e w_e * h_src[e]) / (sum_e w_e);  w = exp(min(leaky_relu(as[s]+ad[d]),30))
template<int CTOT, int H, int VEC, typename TOUT>
__global__ __launch_bounds__(256) void agg_kernel(
        const bf16* __restrict__ hbuf,
        const float* __restrict__ as, const float* __restrict__ ad,
        const int* __restrict__ row_ptr, const int* __restrict__ col_src,
        const float* __restrict__ bias,
        TOUT* __restrict__ outp, int n, int apply_elu) {
    int lane = threadIdx.x & 63;
    int node = blockIdx.x * 4 + (threadIdx.x >> 6);
    if (node >= n) return;
    const int c0 = lane * VEC;
    const int head = c0 >> 6;
    int start = row_ptr[node], end = row_ptr[node + 1];
    float adn = ad[(size_t)node * H + head];
    float acc[VEC] = {};
    float denom = 0.f;

    auto edge_w = [&](int s) -> float {
        float x = as[(size_t)s * H + head] + adn;
        x = (x > 0.f) ? x : 0.2f * x;            // leaky_relu 0.2
        return __expf(fminf(x, 30.f));
    };
    auto loadH = [&](int s, float* o) {
        const bf16* p = hbuf + (size_t)s * CTOT + c0;
        if constexpr (VEC == 4) {
            union { uint2 u; unsigned short us[4]; } cv;
            cv.u = *(const uint2*)p;
            #pragma unroll
            for (int v = 0; v < 4; ++v) o[v] = bfbits2f(cv.us[v]);
        } else {
            o[0] = bfbits2f(*(const unsigned short*)p);
        }
    };

    int e = start;
    for (; e + 4 <= end; e += 4) {
        int s0 = col_src[e], s1 = col_src[e + 1], s2 = col_src[e + 2], s3 = col_src[e + 3];
        if ((unsigned)s0 >= (unsigned)n) s0 = node;
        if ((unsigned)s1 >= (unsigned)n) s1 = node;
        if ((unsigned)s2 >= (unsigned)n) s2 = node;
        if ((unsigned)s3 >= (unsigned)n) s3 = node;
        float h0[VEC], h1[VEC], h2[VEC], h3[VEC];
        loadH(s0, h0); loadH(s1, h1); loadH(s2, h2); loadH(s3, h3);
        float w0 = edge_w(s0), w1 = edge_w(s1), w2 = edge_w(s2), w3 = edge_w(s3);
        denom += (w0 + w1) + (w2 + w3);
        #pragma unroll
        for (int v = 0; v < VEC; ++v)
            acc[v] += w0 * h0[v] + w1 * h1[v] + w2 * h2[v] + w3 * h3[v];
    }
    for (; e < end; ++e) {
        int s = col_src[e];
        if ((unsigned)s >= (unsigned)n) s = node;
        float hv[VEC];
        loadH(s, hv);
        float w = edge_w(s);
        denom += w;
        #pragma unroll
        for (int v = 0; v < VEC; ++v) acc[v] += w * hv[v];
    }
    float inv = 1.f / (denom + 1e-16f);
    float o[VEC];
    #pragma unroll
    for (int v = 0; v < VEC; ++v) {
        o[v] = acc[v] * inv + bias[c0 + v];
        if (apply_elu) o[v] = (o[v] > 0.f) ? o[v] : (__expf(o[v]) - 1.f);
    }
    if constexpr (VEC == 4) {
        // bf16 vector store (8B)
        union { uint2 u; unsigned short us[4]; } cv;
        #pragma unroll
        for (int v = 0; v < 4; ++v) cv.us[v] = f2bf_bits(o[v]);
        *(uint2*)((bf16*)outp + (size_t)node * CTOT + c0) = cv.u;
    } else {
        outp[(size_t)node * CTOT + c0] = (TOUT)o[0];
    }
}

extern "C" void kernel_launch(void* const* d_in, const int* in_sizes, int n_in,
                              void* d_out, int out_size, void* d_ws, size_t ws_size,
                              hipStream_t stream) {
    const float* x   = (const float*)d_in[0];
    const int*   ei  = (const int*)d_in[1];
    const float* W0  = (const float*)d_in[2];
    const float* as0 = (const float*)d_in[3];
    const float* ad0 = (const float*)d_in[4];
    const float* b0  = (const float*)d_in[5];
    const float* W1  = (const float*)d_in[6];
    const float* as1 = (const float*)d_in[7];
    const float* ad1 = (const float*)d_in[8];
    const float* b1  = (const float*)d_in[9];
    const float* W2  = (const float*)d_in[10];
    const float* as2 = (const float*)d_in[11];
    const float* ad2 = (const float*)d_in[12];
    const float* b2  = (const float*)d_in[13];
    float* out = (float*)d_out;

    const int n = in_sizes[0] / 128;   // 50000
    const int E = in_sizes[1] / 2;     // 800000
    const int* esrc = ei;
    const int* edst = ei + E;

    // workspace (~57 MB)
    char* ws = (char*)d_ws;
    bf16* hb0 = (bf16*)ws;                                   // n*256 bf16
    bf16* hb1 = hb0 + (size_t)n * 256;                       // n*256 bf16
    bf16* wt0 = hb1 + (size_t)n * 256;                       // 256*128
    bf16* wt1 = wt0 + 128 * 256;                             // 256*256
    bf16* wt2 = wt1 + 256 * 256;                             // 64*256
    float* asb = (float*)(wt2 + 256 * 64);                   // n*4 fp32
    float* adb = asb + (size_t)n * 4;                        // n*4 fp32
    int* row_ptr = (int*)(adb + (size_t)n * 4);              // n+1 (+pad)
    int* cursor  = row_ptr + (n + 64);                       // n
    int* col_src = cursor + n;                               // E+n

    // ---- weight transposes (bf16) + CSR build ----
    transpose_kernel<<<(128 * 256 + 255) / 256, 256, 0, stream>>>(W0, wt0, 128, 256);
    transpose_kernel<<<(256 * 256 + 255) / 256, 256, 0, stream>>>(W1, wt1, 256, 256);
    transpose_kernel<<<(256 * 64 + 255) / 256, 256, 0, stream>>>(W2, wt2, 256, 64);
    init_counts_kernel<<<(n + 255) / 256, 256, 0, stream>>>(cursor, n);
    hist_kernel<<<(E + 255) / 256, 256, 0, stream>>>(edst, cursor, E, n);
    scan_kernel<<<1, 1024, 0, stream>>>(cursor, row_ptr, n);
    scatter_kernel<<<(E + n + 255) / 256, 256, 0, stream>>>(esrc, edst, cursor, col_src, E, n);

    dim3 blk(256);
    int mg = (n + 63) / 64;
    int ag = (n + 3) / 4;   // 4 nodes (waves) per block
    // ---- layer 0: x[n,128] @ W0[128,256] ----
    {
        mfma_gemm_kernel<float><<<dim3(mg, 4), blk, 0, stream>>>(x, wt0, hb0, n, 128, 256);
        alpha_kernel<4><<<ag, blk, 0, stream>>>(hb0, as0, ad0, asb, adb, n);
        agg_kernel<256, 4, 4, bf16><<<ag, blk, 0, stream>>>(hb0, asb, adb, row_ptr, col_src,
                                                            b0, hb1, n, 1);
    }
    // ---- layer 1: h[n,256] @ W1[256,256] ----
    {
        mfma_gemm_kernel<bf16><<<dim3(mg, 4), blk, 0, stream>>>(hb1, wt1, hb0, n, 256, 256);
        alpha_kernel<4><<<ag, blk, 0, stream>>>(hb0, as1, ad1, asb, adb, n);
        agg_kernel<256, 4, 4, bf16><<<ag, blk, 0, stream>>>(hb0, asb, adb, row_ptr, col_src,
                                                            b1, hb1, n, 1);
    }
    // ---- layer 2: h[n,256] @ W2[256,64], heads=1, no ELU, fp32 out ----
    {
        mfma_gemm_kernel<bf16><<<dim3(mg, 1), blk, 0, stream>>>(hb1, wt2, hb0, n, 256, 64);
        alpha_kernel<1><<<ag, blk, 0, stream>>>(hb0, as2, ad2, asb, adb, n);
        agg_kernel<64, 1, 1, float><<<ag, blk, 0, stream>>>(hb0, asb, adb, row_ptr, col_src,
                                                            b2, out, n, 0);
    }
}

// Round 7
// 502.789 us; speedup vs baseline: 2.6375x; 1.0565x over previous
//
#include <hip/hip_runtime.h>
#include <hip/hip_bf16.h>

typedef __hip_bfloat16 bf16;
typedef short s8v __attribute__((ext_vector_type(8)));   // 8 bf16 (4 VGPRs)
typedef float f32x4 __attribute__((ext_vector_type(4))); // MFMA accumulator

__device__ __forceinline__ unsigned short f2bf_bits(float x) {
    union { bf16 h; unsigned short u; } v; v.h = __float2bfloat16(x); return v.u;
}
__device__ __forceinline__ float bfbits2f(unsigned short u) {
    union { unsigned u32; float f; } v; v.u32 = ((unsigned)u) << 16; return v.f;
}

// async global->LDS, 16B per lane; LDS dest must be uniform base + lane*16
template<typename T>
__device__ __forceinline__ void gload_lds16(const T* g, T* l) {
    __builtin_amdgcn_global_load_lds(
        (const __attribute__((address_space(1))) unsigned int*)g,
        (__attribute__((address_space(3))) unsigned int*)l, 16, 0, 0);
}

__device__ __forceinline__ uint4 load8(const bf16* p) { return *(const uint4*)p; }

// ---------------- fp32 -> bf16 convert (x, one-time) ----------------
__global__ void convert_kernel(const float* __restrict__ x, bf16* __restrict__ xb, int total4) {
    int i = blockIdx.x * blockDim.x + threadIdx.x;
    if (i >= total4) return;
    float4 f = *(const float4*)(x + (size_t)i * 4);
    union { uint2 u; unsigned short us[4]; } cv;
    cv.us[0] = f2bf_bits(f.x); cv.us[1] = f2bf_bits(f.y);
    cv.us[2] = f2bf_bits(f.z); cv.us[3] = f2bf_bits(f.w);
    *(uint2*)(xb + (size_t)i * 4) = cv.u;
}

// ---------------- CSR build ----------------
__global__ void init_counts_kernel(int* counts, int n) {
    int i = blockIdx.x * blockDim.x + threadIdx.x;
    if (i < n) counts[i] = 1;  // one self-loop per node
}

__global__ void hist_kernel(const int* __restrict__ dst, int* counts, int E, int n) {
    int i = blockIdx.x * blockDim.x + threadIdx.x;
    if (i < E) {
        int d = dst[i];
        if ((unsigned)d < (unsigned)n) atomicAdd(&counts[d], 1);
    }
}

__global__ void scan_kernel(int* counts, int* row_ptr, int n) {
    __shared__ int wsum[16];
    __shared__ int woff[16];
    int tid = threadIdx.x;
    int lane = tid & 63;
    int wid = tid >> 6;
    int base = 0;
    for (int off = 0; off < n; off += 1024) {
        int i = off + tid;
        int v = (i < n) ? counts[i] : 0;
        int incl = v;
        #pragma unroll
        for (int d = 1; d < 64; d <<= 1) {
            int t = __shfl_up(incl, d, 64);
            if (lane >= d) incl += t;
        }
        if (lane == 63) wsum[wid] = incl;
        __syncthreads();
        if (wid == 0) {
            int wv = (lane < 16) ? wsum[lane] : 0;
            int wincl = wv;
            #pragma unroll
            for (int d = 1; d < 16; d <<= 1) {
                int t = __shfl_up(wincl, d, 64);
                if (lane >= d) wincl += t;
            }
            if (lane < 16) woff[lane] = wincl - wv;
        }
        __syncthreads();
        int chunk_total = woff[15] + wsum[15];
        if (i < n) {
            int excl = base + woff[wid] + incl - v;
            row_ptr[i] = excl;
            counts[i] = excl;  // cursor
        }
        base += chunk_total;
        __syncthreads();
    }
    if (tid == 0) row_ptr[n] = base;
}

__global__ void scatter_kernel(const int* __restrict__ src, const int* __restrict__ dst,
                               int* cursor, int* col_src, int E, int n) {
    int i = blockIdx.x * blockDim.x + threadIdx.x;
    if (i < E) {
        int d = dst[i];
        if ((unsigned)d >= (unsigned)n) return;
        int s = src[i];
        if ((unsigned)s >= (unsigned)n) s = d;
        int pos = atomicAdd(&cursor[d], 1);
        col_src[pos] = s;
    } else if (i < E + n) {
        int v = i - E;
        int pos = atomicAdd(&cursor[v], 1);
        col_src[pos] = v;  // self-loop
    }
}

// ---------------- W[k][n] fp32 -> Wt[n][k] bf16 (one-time, L2-resident) ----------------
__global__ void transpose_kernel(const float* __restrict__ W, bf16* __restrict__ Wt,
                                 int K, int N) {
    int idx = blockIdx.x * blockDim.x + threadIdx.x;
    if (idx >= K * N) return;
    int nn = idx / K, k = idx - nn * K;
    Wt[idx] = __float2bfloat16(W[(size_t)k * N + nn]);
}

// ---------------- 128x128 MFMA GEMM + fused alpha epilogue ----------------
// C[M,N] = A[M,K] @ W[K,N] (Wt = W^T [n][k] bf16), BK=64, 4 waves in 2x2 quadrants.
// global_load_lds staging with XOR chunk swizzle: LDS(row, c) = global chunk c^(row&7).
// Epilogue: C bf16 store + atomicAdd partial dots as/ad (wave's 64 cols = one head).
__global__ __launch_bounds__(256) void gemm128_kernel(
        const bf16* __restrict__ A, const bf16* __restrict__ Wt, bf16* __restrict__ C,
        const float* __restrict__ a_src, const float* __restrict__ a_dst,
        float* __restrict__ asb, float* __restrict__ adb,
        int M, int K, int N, int H) {
    __shared__ __align__(16) bf16 As[128 * 64];
    __shared__ __align__(16) bf16 Bs[128 * 64];
    int tid = threadIdx.x;
    int w = tid >> 6, l = tid & 63;
    int lm = l & 15, quad = l >> 4;
    int m0 = blockIdx.x * 128, n0 = blockIdx.y * 128;
    int wr = (w >> 1) * 64, wc = (w & 1) * 64;
    int srow = w * 32 + (l >> 3);   // staging row (+ j*8)
    int schunk = l & 7;             // staging LDS chunk
    f32x4 acc[4][4] = {};
    for (int kt = 0; kt < K; kt += 64) {
        #pragma unroll
        for (int j = 0; j < 4; ++j) {
            int row = srow + j * 8;
            int g = schunk ^ (row & 7);       // global chunk fetched into LDS chunk schunk
            int m = m0 + row; if (m >= M) m = M - 1;  // clamp: dup rows, never stored
            gload_lds16(A + (size_t)m * K + kt + g * 8, As + row * 64 + schunk * 8);
            gload_lds16(Wt + (size_t)(n0 + row) * K + kt + g * 8, Bs + row * 64 + schunk * 8);
        }
        __syncthreads();
        #pragma unroll
        for (int ks = 0; ks < 2; ++ks) {
            s8v a[4], b[4];
            #pragma unroll
            for (int mi = 0; mi < 4; ++mi) {
                int row = wr + mi * 16 + lm;
                int c = (ks * 4 + quad) ^ (row & 7);
                a[mi] = *(const s8v*)(As + row * 64 + c * 8);
            }
            #pragma unroll
            for (int ni = 0; ni < 4; ++ni) {
                int row = wc + ni * 16 + lm;
                int c = (ks * 4 + quad) ^ (row & 7);
                b[ni] = *(const s8v*)(Bs + row * 64 + c * 8);
            }
            #pragma unroll
            for (int mi = 0; mi < 4; ++mi)
                #pragma unroll
                for (int ni = 0; ni < 4; ++ni)
                    acc[mi][ni] = __builtin_amdgcn_mfma_f32_16x16x32_bf16(
                        a[mi], b[ni], acc[mi][ni], 0, 0, 0);
        }
        __syncthreads();
    }
    // epilogue: store C + fused alpha partials (wave cols [n0+wc, +64) = one head)
    int head = (n0 + wc) >> 6;
    float a_s[4], a_d[4];
    #pragma unroll
    for (int ni = 0; ni < 4; ++ni) {
        int col = n0 + wc + ni * 16 + lm;
        a_s[ni] = a_src[col];
        a_d[ni] = a_dst[col];
    }
    #pragma unroll
    for (int mi = 0; mi < 4; ++mi) {
        #pragma unroll
        for (int reg = 0; reg < 4; ++reg) {
            int m = m0 + wr + mi * 16 + quad * 4 + reg;
            float ps = 0.f, pd = 0.f;
            #pragma unroll
            for (int ni = 0; ni < 4; ++ni) {
                float v = acc[mi][ni][reg];
                ps += v * a_s[ni];
                pd += v * a_d[ni];
                if (m < M)
                    C[(size_t)m * N + n0 + wc + ni * 16 + lm] = __float2bfloat16(v);
            }
            #pragma unroll
            for (int d = 1; d < 16; d <<= 1) {
                ps += __shfl_xor(ps, d, 64);
                pd += __shfl_xor(pd, d, 64);
            }
            if (lm == 0 && m < M) {
                atomicAdd(&asb[(size_t)m * H + head], ps);
                atomicAdd(&adb[(size_t)m * H + head], pd);
            }
        }
    }
}

// ---------------- 64x64 MFMA GEMM + fused alpha (layer 2, N=64, H=1) ----------------
__global__ __launch_bounds__(256) void gemm64_kernel(
        const bf16* __restrict__ A, const bf16* __restrict__ Wt, bf16* __restrict__ C,
        const float* __restrict__ a_src, const float* __restrict__ a_dst,
        float* __restrict__ asb, float* __restrict__ adb,
        int M, int K, int N) {
    __shared__ __align__(16) bf16 As[64][72];
    __shared__ __align__(16) bf16 Bs[64][72];
    int tid = threadIdx.x;
    int m0 = blockIdx.x * 64;
    int w = tid >> 6;
    int l = tid & 63;
    int lm = l & 15;
    int quad = l >> 4;
    int r = tid >> 2;
    int kb = (tid & 3) * 8;
    f32x4 acc[4] = {};
    int mstage = m0 + r;
    for (int kt = 0; kt < K; kt += 64) {
        #pragma unroll
        for (int c = 0; c < 2; ++c) {
            int kk = kb + c * 32;
            uint4 av = (mstage < M) ? load8(&A[(size_t)mstage * K + kt + kk])
                                    : make_uint4(0, 0, 0, 0);
            *(uint4*)&As[r][kk] = av;
            *(uint4*)&Bs[r][kk] = load8(&Wt[(size_t)r * K + kt + kk]);
        }
        __syncthreads();
        #pragma unroll
        for (int ks = 0; ks < 2; ++ks) {
            s8v a = *(const s8v*)&As[w * 16 + lm][ks * 32 + quad * 8];
            #pragma unroll
            for (int nb = 0; nb < 4; ++nb) {
                s8v b = *(const s8v*)&Bs[nb * 16 + lm][ks * 32 + quad * 8];
                acc[nb] = __builtin_amdgcn_mfma_f32_16x16x32_bf16(a, b, acc[nb], 0, 0, 0);
            }
        }
        __syncthreads();
    }
    float a_s[4], a_d[4];
    #pragma unroll
    for (int nb = 0; nb < 4; ++nb) {
        a_s[nb] = a_src[nb * 16 + lm];
        a_d[nb] = a_dst[nb * 16 + lm];
    }
    #pragma unroll
    for (int reg = 0; reg < 4; ++reg) {
        int m = m0 + w * 16 + quad * 4 + reg;
        float ps = 0.f, pd = 0.f;
        #pragma unroll
        for (int nb = 0; nb < 4; ++nb) {
            float v = acc[nb][reg];
            ps += v * a_s[nb];
            pd += v * a_d[nb];
            if (m < M)
                C[(size_t)m * N + nb * 16 + lm] = __float2bfloat16(v);
        }
        #pragma unroll
        for (int d = 1; d < 16; d <<= 1) {
            ps += __shfl_xor(ps, d, 64);
            pd += __shfl_xor(pd, d, 64);
        }
        if (lm == 0 && m < M) {
            atomicAdd(&asb[m], ps);
            atomicAdd(&adb[m], pd);
        }
    }
}

// ---------------- edge softmax + aggregation, SINGLE PASS, channel-vectorized --------
template<int CTOT, int H, int VEC, typename TOUT>
__global__ __launch_bounds__(256) void agg_kernel(
        const bf16* __restrict__ hbuf,
        const float* __restrict__ as, const float* __restrict__ ad,
        const int* __restrict__ row_ptr, const int* __restrict__ col_src,
        const float* __restrict__ bias,
        TOUT* __restrict__ outp, int n, int apply_elu) {
    int lane = threadIdx.x & 63;
    int node = blockIdx.x * 4 + (threadIdx.x >> 6);
    if (node >= n) return;
    const int c0 = lane * VEC;
    const int head = c0 >> 6;
    int start = row_ptr[node], end = row_ptr[node + 1];
    float adn = ad[(size_t)node * H + head];
    float acc[VEC] = {};
    float denom = 0.f;

    auto edge_w = [&](int s) -> float {
        float x = as[(size_t)s * H + head] + adn;
        x = (x > 0.f) ? x : 0.2f * x;            // leaky_relu 0.2
        return __expf(fminf(x, 30.f));
    };
    auto loadH = [&](int s, float* o) {
        const bf16* p = hbuf + (size_t)s * CTOT + c0;
        if constexpr (VEC == 4) {
            union { uint2 u; unsigned short us[4]; } cv;
            cv.u = *(const uint2*)p;
            #pragma unroll
            for (int v = 0; v < 4; ++v) o[v] = bfbits2f(cv.us[v]);
        } else {
            o[0] = bfbits2f(*(const unsigned short*)p);
        }
    };

    int e = start;
    for (; e + 4 <= end; e += 4) {
        int s0 = col_src[e], s1 = col_src[e + 1], s2 = col_src[e + 2], s3 = col_src[e + 3];
        if ((unsigned)s0 >= (unsigned)n) s0 = node;
        if ((unsigned)s1 >= (unsigned)n) s1 = node;
        if ((unsigned)s2 >= (unsigned)n) s2 = node;
        if ((unsigned)s3 >= (unsigned)n) s3 = node;
        float h0[VEC], h1[VEC], h2[VEC], h3[VEC];
        loadH(s0, h0); loadH(s1, h1); loadH(s2, h2); loadH(s3, h3);
        float w0 = edge_w(s0), w1 = edge_w(s1), w2 = edge_w(s2), w3 = edge_w(s3);
        denom += (w0 + w1) + (w2 + w3);
        #pragma unroll
        for (int v = 0; v < VEC; ++v)
            acc[v] += w0 * h0[v] + w1 * h1[v] + w2 * h2[v] + w3 * h3[v];
    }
    for (; e < end; ++e) {
        int s = col_src[e];
        if ((unsigned)s >= (unsigned)n) s = node;
        float hv[VEC];
        loadH(s, hv);
        float w = edge_w(s);
        denom += w;
        #pragma unroll
        for (int v = 0; v < VEC; ++v) acc[v] += w * hv[v];
    }
    float inv = 1.f / (denom + 1e-16f);
    float o[VEC];
    #pragma unroll
    for (int v = 0; v < VEC; ++v) {
        o[v] = acc[v] * inv + bias[c0 + v];
        if (apply_elu) o[v] = (o[v] > 0.f) ? o[v] : (__expf(o[v]) - 1.f);
    }
    if constexpr (VEC == 4) {
        union { uint2 u; unsigned short us[4]; } cv;
        #pragma unroll
        for (int v = 0; v < 4; ++v) cv.us[v] = f2bf_bits(o[v]);
        *(uint2*)((bf16*)outp + (size_t)node * CTOT + c0) = cv.u;
    } else {
        outp[(size_t)node * CTOT + c0] = (TOUT)o[0];
    }
}

extern "C" void kernel_launch(void* const* d_in, const int* in_sizes, int n_in,
                              void* d_out, int out_size, void* d_ws, size_t ws_size,
                              hipStream_t stream) {
    const float* x   = (const float*)d_in[0];
    const int*   ei  = (const int*)d_in[1];
    const float* W0  = (const float*)d_in[2];
    const float* as0 = (const float*)d_in[3];
    const float* ad0 = (const float*)d_in[4];
    const float* b0  = (const float*)d_in[5];
    const float* W1  = (const float*)d_in[6];
    const float* as1 = (const float*)d_in[7];
    const float* ad1 = (const float*)d_in[8];
    const float* b1  = (const float*)d_in[9];
    const float* W2  = (const float*)d_in[10];
    const float* as2 = (const float*)d_in[11];
    const float* ad2 = (const float*)d_in[12];
    const float* b2  = (const float*)d_in[13];
    float* out = (float*)d_out;

    const int n = in_sizes[0] / 128;   // 50000
    const int E = in_sizes[1] / 2;     // 800000
    const int* esrc = ei;
    const int* edst = ei + E;

    // workspace (~73 MB)
    char* ws = (char*)d_ws;
    bf16* hb0 = (bf16*)ws;                                   // n*256 bf16
    bf16* hb1 = hb0 + (size_t)n * 256;                       // n*256 bf16
    bf16* xb  = hb1 + (size_t)n * 256;                       // n*128 bf16
    bf16* wt0 = xb + (size_t)n * 128;                        // 256*128
    bf16* wt1 = wt0 + 128 * 256;                             // 256*256
    bf16* wt2 = wt1 + 256 * 256;                             // 64*256
    float* asb = (float*)(wt2 + 256 * 64);                   // n*4 fp32
    float* adb = asb + (size_t)n * 4;                        // n*4 fp32 (contiguous w/ asb)
    int* row_ptr = (int*)(adb + (size_t)n * 4);              // n+1 (+pad)
    int* cursor  = row_ptr + (n + 64);                       // n
    int* col_src = cursor + n;                               // E+n

    // ---- one-time prep: x->bf16, weight transposes, CSR ----
    convert_kernel<<<(n * 128 / 4 + 255) / 256, 256, 0, stream>>>(x, xb, n * 128 / 4);
    transpose_kernel<<<(128 * 256 + 255) / 256, 256, 0, stream>>>(W0, wt0, 128, 256);
    transpose_kernel<<<(256 * 256 + 255) / 256, 256, 0, stream>>>(W1, wt1, 256, 256);
    transpose_kernel<<<(256 * 64 + 255) / 256, 256, 0, stream>>>(W2, wt2, 256, 64);
    init_counts_kernel<<<(n + 255) / 256, 256, 0, stream>>>(cursor, n);
    hist_kernel<<<(E + 255) / 256, 256, 0, stream>>>(edst, cursor, E, n);
    scan_kernel<<<1, 1024, 0, stream>>>(cursor, row_ptr, n);
    scatter_kernel<<<(E + n + 255) / 256, 256, 0, stream>>>(esrc, edst, cursor, col_src, E, n);

    dim3 blk(256);
    int mg128 = (n + 127) / 128;
    int mg64  = (n + 63) / 64;
    int ag = (n + 3) / 4;
    size_t alpha_bytes = (size_t)n * 8 * sizeof(float);  // asb+adb contiguous

    // ---- layer 0: x[n,128] @ W0[128,256] ----
    hipMemsetAsync(asb, 0, alpha_bytes, stream);
    gemm128_kernel<<<dim3(mg128, 2), blk, 0, stream>>>(xb, wt0, hb0, as0, ad0,
                                                       asb, adb, n, 128, 256, 4);
    agg_kernel<256, 4, 4, bf16><<<ag, blk, 0, stream>>>(hb0, asb, adb, row_ptr, col_src,
                                                        b0, hb1, n, 1);
    // ---- layer 1: h[n,256] @ W1[256,256] ----
    hipMemsetAsync(asb, 0, alpha_bytes, stream);
    gemm128_kernel<<<dim3(mg128, 2), blk, 0, stream>>>(hb1, wt1, hb0, as1, ad1,
                                                       asb, adb, n, 256, 256, 4);
    agg_kernel<256, 4, 4, bf16><<<ag, blk, 0, stream>>>(hb0, asb, adb, row_ptr, col_src,
                                                        b1, hb1, n, 1);
    // ---- layer 2: h[n,256] @ W2[256,64], heads=1, no ELU, fp32 out ----
    hipMemsetAsync(asb, 0, alpha_bytes, stream);
    gemm64_kernel<<<dim3(mg64, 1), blk, 0, stream>>>(hb1, wt2, hb0, as2, ad2,
                                                     asb, adb, n, 256, 64);
    agg_kernel<64, 1, 1, float><<<ag, blk, 0, stream>>>(hb0, asb, adb, row_ptr, col_src,
                                                        b2, out, n, 0);
}

// Round 8
// 476.876 us; speedup vs baseline: 2.7809x; 1.0543x over previous
//
#include <hip/hip_runtime.h>
#include <hip/hip_bf16.h>

typedef __hip_bfloat16 bf16;
typedef short s8v __attribute__((ext_vector_type(8)));   // 8 bf16 (4 VGPRs)
typedef float f32x4 __attribute__((ext_vector_type(4))); // MFMA accumulator

__device__ __forceinline__ unsigned short f2bf_bits(float x) {
    union { bf16 h; unsigned short u; } v; v.h = __float2bfloat16(x); return v.u;
}
__device__ __forceinline__ float bfbits2f(unsigned short u) {
    union { unsigned u32; float f; } v; v.u32 = ((unsigned)u) << 16; return v.f;
}

// async global->LDS, 16B per lane; LDS dest must be uniform base + lane*16
template<typename T>
__device__ __forceinline__ void gload_lds16(const T* g, T* l) {
    __builtin_amdgcn_global_load_lds(
        (const __attribute__((address_space(1))) unsigned int*)g,
        (__attribute__((address_space(3))) unsigned int*)l, 16, 0, 0);
}

__device__ __forceinline__ uint4 load8(const bf16* p) { return *(const uint4*)p; }

// ---------------- fp32 -> bf16 convert (x, one-time) ----------------
__global__ void convert_kernel(const float* __restrict__ x, bf16* __restrict__ xb, int total4) {
    int i = blockIdx.x * blockDim.x + threadIdx.x;
    if (i >= total4) return;
    float4 f = *(const float4*)(x + (size_t)i * 4);
    union { uint2 u; unsigned short us[4]; } cv;
    cv.us[0] = f2bf_bits(f.x); cv.us[1] = f2bf_bits(f.y);
    cv.us[2] = f2bf_bits(f.z); cv.us[3] = f2bf_bits(f.w);
    *(uint2*)(xb + (size_t)i * 4) = cv.u;
}

// ---------------- all 3 weight transposes in one dispatch ----------------
// W[k][n] fp32 -> Wt[n][k] bf16
__device__ __forceinline__ void tr1(const float* W, bf16* Wt, int idx, int K, int N) {
    int nn = idx / K, k = idx - nn * K;
    Wt[idx] = __float2bfloat16(W[(size_t)k * N + nn]);
}
__global__ void transpose_all_kernel(const float* __restrict__ W0, const float* __restrict__ W1,
                                     const float* __restrict__ W2, bf16* __restrict__ wt0,
                                     bf16* __restrict__ wt1, bf16* __restrict__ wt2) {
    int idx = blockIdx.x * blockDim.x + threadIdx.x;
    if (idx < 32768) tr1(W0, wt0, idx, 128, 256);                       // 128x256
    else if (idx < 32768 + 65536) tr1(W1, wt1, idx - 32768, 256, 256);  // 256x256
    else if (idx < 32768 + 65536 + 16384) tr1(W2, wt2, idx - 98304, 256, 64);
}

// ---------------- CSR build ----------------
__global__ void hist_kernel(const int* __restrict__ dst, int* counts, int E, int n) {
    int i = blockIdx.x * blockDim.x + threadIdx.x;
    if (i < E) {
        int d = dst[i];
        if ((unsigned)d < (unsigned)n) atomicAdd(&counts[d], 1);
    }
}

// hierarchical scan, phase 1: per-block (1024) local exclusive scan of counts[i]+1
__global__ __launch_bounds__(1024) void scan_phase1(
        const int* __restrict__ counts, int* __restrict__ excl_out,
        int* __restrict__ blocksums, int n) {
    __shared__ int wsum[16];
    __shared__ int woff[16];
    int tid = threadIdx.x, lane = tid & 63, wid = tid >> 6;
    int i = blockIdx.x * 1024 + tid;
    int v = (i < n) ? counts[i] + 1 : 0;   // +1 = self-loop
    int incl = v;
    #pragma unroll
    for (int d = 1; d < 64; d <<= 1) {
        int t = __shfl_up(incl, d, 64);
        if (lane >= d) incl += t;
    }
    if (lane == 63) wsum[wid] = incl;
    __syncthreads();
    if (wid == 0) {
        int wv = (lane < 16) ? wsum[lane] : 0;
        int wincl = wv;
        #pragma unroll
        for (int d = 1; d < 16; d <<= 1) {
            int t = __shfl_up(wincl, d, 64);
            if (lane >= d) wincl += t;
        }
        if (lane < 16) woff[lane] = wincl - wv;
    }
    __syncthreads();
    if (i < n) excl_out[i] = woff[wid] + incl - v;
    if (tid == 1023) blocksums[blockIdx.x] = woff[15] + wsum[15];
}

// phase 2: every wave redundantly scans the <=64 block sums; apply offsets
__global__ __launch_bounds__(1024) void scan_phase2(
        const int* __restrict__ blocksums, int* __restrict__ row_ptr,
        int* __restrict__ cursor, int nb, int n) {
    int tid = threadIdx.x, lane = tid & 63;
    int i = blockIdx.x * 1024 + tid;
    int v = (lane < nb) ? blocksums[lane] : 0;
    int incl = v;
    #pragma unroll
    for (int d = 1; d < 64; d <<= 1) {
        int t = __shfl_up(incl, d, 64);
        if (lane >= d) incl += t;
    }
    int excl_lane = incl - v;
    int base = __shfl(excl_lane, blockIdx.x, 64);
    int total = __shfl(incl, nb - 1, 64);
    if (i < n) {
        int val = row_ptr[i] + base;
        row_ptr[i] = val;
        cursor[i] = val;
    }
    if (blockIdx.x == 0 && tid == 0) row_ptr[n] = total;
}

__global__ void scatter_kernel(const int* __restrict__ src, const int* __restrict__ dst,
                               int* cursor, int* col_src, int E, int n) {
    int i = blockIdx.x * blockDim.x + threadIdx.x;
    if (i < E) {
        int d = dst[i];
        if ((unsigned)d >= (unsigned)n) return;
        int s = src[i];
        if ((unsigned)s >= (unsigned)n) s = d;
        int pos = atomicAdd(&cursor[d], 1);
        col_src[pos] = s;
    } else if (i < E + n) {
        int v = i - E;
        int pos = atomicAdd(&cursor[v], 1);
        col_src[pos] = v;  // self-loop
    }
}

// ---------------- 128x128 MFMA GEMM + fused alpha epilogue ----------------
__global__ __launch_bounds__(256) void gemm128_kernel(
        const bf16* __restrict__ A, const bf16* __restrict__ Wt, bf16* __restrict__ C,
        const float* __restrict__ a_src, const float* __restrict__ a_dst,
        float* __restrict__ asb, float* __restrict__ adb,
        int M, int K, int N, int H) {
    __shared__ __align__(16) bf16 As[128 * 64];
    __shared__ __align__(16) bf16 Bs[128 * 64];
    int tid = threadIdx.x;
    int w = tid >> 6, l = tid & 63;
    int lm = l & 15, quad = l >> 4;
    int m0 = blockIdx.x * 128, n0 = blockIdx.y * 128;
    int wr = (w >> 1) * 64, wc = (w & 1) * 64;
    int srow = w * 32 + (l >> 3);
    int schunk = l & 7;
    f32x4 acc[4][4] = {};
    for (int kt = 0; kt < K; kt += 64) {
        #pragma unroll
        for (int j = 0; j < 4; ++j) {
            int row = srow + j * 8;
            int g = schunk ^ (row & 7);
            int m = m0 + row; if (m >= M) m = M - 1;  // clamp: dup rows, never stored
            gload_lds16(A + (size_t)m * K + kt + g * 8, As + row * 64 + schunk * 8);
            gload_lds16(Wt + (size_t)(n0 + row) * K + kt + g * 8, Bs + row * 64 + schunk * 8);
        }
        __syncthreads();
        #pragma unroll
        for (int ks = 0; ks < 2; ++ks) {
            s8v a[4], b[4];
            #pragma unroll
            for (int mi = 0; mi < 4; ++mi) {
                int row = wr + mi * 16 + lm;
                int c = (ks * 4 + quad) ^ (row & 7);
                a[mi] = *(const s8v*)(As + row * 64 + c * 8);
            }
            #pragma unroll
            for (int ni = 0; ni < 4; ++ni) {
                int row = wc + ni * 16 + lm;
                int c = (ks * 4 + quad) ^ (row & 7);
                b[ni] = *(const s8v*)(Bs + row * 64 + c * 8);
            }
            #pragma unroll
            for (int mi = 0; mi < 4; ++mi)
                #pragma unroll
                for (int ni = 0; ni < 4; ++ni)
                    acc[mi][ni] = __builtin_amdgcn_mfma_f32_16x16x32_bf16(
                        a[mi], b[ni], acc[mi][ni], 0, 0, 0);
        }
        __syncthreads();
    }
    int head = (n0 + wc) >> 6;
    float a_s[4], a_d[4];
    #pragma unroll
    for (int ni = 0; ni < 4; ++ni) {
        int col = n0 + wc + ni * 16 + lm;
        a_s[ni] = a_src[col];
        a_d[ni] = a_dst[col];
    }
    #pragma unroll
    for (int mi = 0; mi < 4; ++mi) {
        #pragma unroll
        for (int reg = 0; reg < 4; ++reg) {
            int m = m0 + wr + mi * 16 + quad * 4 + reg;
            float ps = 0.f, pd = 0.f;
            #pragma unroll
            for (int ni = 0; ni < 4; ++ni) {
                float v = acc[mi][ni][reg];
                ps += v * a_s[ni];
                pd += v * a_d[ni];
                if (m < M)
                    C[(size_t)m * N + n0 + wc + ni * 16 + lm] = __float2bfloat16(v);
            }
            #pragma unroll
            for (int d = 1; d < 16; d <<= 1) {
                ps += __shfl_xor(ps, d, 64);
                pd += __shfl_xor(pd, d, 64);
            }
            if (lm == 0 && m < M) {
                atomicAdd(&asb[(size_t)m * H + head], ps);
                atomicAdd(&adb[(size_t)m * H + head], pd);
            }
        }
    }
}

// ---------------- 64x64 MFMA GEMM + fused alpha (layer 2, N=64, H=1) ----------------
__global__ __launch_bounds__(256) void gemm64_kernel(
        const bf16* __restrict__ A, const bf16* __restrict__ Wt, bf16* __restrict__ C,
        const float* __restrict__ a_src, const float* __restrict__ a_dst,
        float* __restrict__ asb, float* __restrict__ adb,
        int M, int K, int N) {
    __shared__ __align__(16) bf16 As[64][72];
    __shared__ __align__(16) bf16 Bs[64][72];
    int tid = threadIdx.x;
    int m0 = blockIdx.x * 64;
    int w = tid >> 6;
    int l = tid & 63;
    int lm = l & 15;
    int quad = l >> 4;
    int r = tid >> 2;
    int kb = (tid & 3) * 8;
    f32x4 acc[4] = {};
    int mstage = m0 + r;
    for (int kt = 0; kt < K; kt += 64) {
        #pragma unroll
        for (int c = 0; c < 2; ++c) {
            int kk = kb + c * 32;
            uint4 av = (mstage < M) ? load8(&A[(size_t)mstage * K + kt + kk])
                                    : make_uint4(0, 0, 0, 0);
            *(uint4*)&As[r][kk] = av;
            *(uint4*)&Bs[r][kk] = load8(&Wt[(size_t)r * K + kt + kk]);
        }
        __syncthreads();
        #pragma unroll
        for (int ks = 0; ks < 2; ++ks) {
            s8v a = *(const s8v*)&As[w * 16 + lm][ks * 32 + quad * 8];
            #pragma unroll
            for (int nb = 0; nb < 4; ++nb) {
                s8v b = *(const s8v*)&Bs[nb * 16 + lm][ks * 32 + quad * 8];
                acc[nb] = __builtin_amdgcn_mfma_f32_16x16x32_bf16(a, b, acc[nb], 0, 0, 0);
            }
        }
        __syncthreads();
    }
    float a_s[4], a_d[4];
    #pragma unroll
    for (int nb = 0; nb < 4; ++nb) {
        a_s[nb] = a_src[nb * 16 + lm];
        a_d[nb] = a_dst[nb * 16 + lm];
    }
    #pragma unroll
    for (int reg = 0; reg < 4; ++reg) {
        int m = m0 + w * 16 + quad * 4 + reg;
        float ps = 0.f, pd = 0.f;
        #pragma unroll
        for (int nb = 0; nb < 4; ++nb) {
            float v = acc[nb][reg];
            ps += v * a_s[nb];
            pd += v * a_d[nb];
            if (m < M)
                C[(size_t)m * N + nb * 16 + lm] = __float2bfloat16(v);
        }
        #pragma unroll
        for (int d = 1; d < 16; d <<= 1) {
            ps += __shfl_xor(ps, d, 64);
            pd += __shfl_xor(pd, d, 64);
        }
        if (lm == 0 && m < M) {
            atomicAdd(&asb[m], ps);
            atomicAdd(&adb[m], pd);
        }
    }
}

// ---------------- edge softmax + aggregation, SINGLE PASS, 8-edge unroll --------
template<int CTOT, int H, int VEC, typename TOUT>
__global__ __launch_bounds__(256) void agg_kernel(
        const bf16* __restrict__ hbuf,
        const float* __restrict__ as, const float* __restrict__ ad,
        const int* __restrict__ row_ptr, const int* __restrict__ col_src,
        const float* __restrict__ bias,
        TOUT* __restrict__ outp, int n, int apply_elu) {
    int lane = threadIdx.x & 63;
    int node = blockIdx.x * 4 + (threadIdx.x >> 6);
    if (node >= n) return;
    const int c0 = lane * VEC;
    const int head = c0 >> 6;
    int start = row_ptr[node], end = row_ptr[node + 1];
    float adn = ad[(size_t)node * H + head];
    float acc[VEC] = {};
    float denom = 0.f;

    auto edge_w = [&](int s) -> float {
        float x = as[(size_t)s * H + head] + adn;
        x = (x > 0.f) ? x : 0.2f * x;            // leaky_relu 0.2
        return __expf(fminf(x, 30.f));
    };
    auto loadH = [&](int s, float* o) {
        const bf16* p = hbuf + (size_t)s * CTOT + c0;
        if constexpr (VEC == 4) {
            union { uint2 u; unsigned short us[4]; } cv;
            cv.u = *(const uint2*)p;
            #pragma unroll
            for (int v = 0; v < 4; ++v) o[v] = bfbits2f(cv.us[v]);
        } else {
            o[0] = bfbits2f(*(const unsigned short*)p);
        }
    };

    int e = start;
    for (; e + 8 <= end; e += 8) {
        int s[8];
        float w[8], hv[8][VEC];
        #pragma unroll
        for (int j = 0; j < 8; ++j) {
            s[j] = col_src[e + j];
            if ((unsigned)s[j] >= (unsigned)n) s[j] = node;
        }
        #pragma unroll
        for (int j = 0; j < 8; ++j) loadH(s[j], hv[j]);
        #pragma unroll
        for (int j = 0; j < 8; ++j) w[j] = edge_w(s[j]);
        #pragma unroll
        for (int j = 0; j < 8; ++j) {
            denom += w[j];
            #pragma unroll
            for (int v = 0; v < VEC; ++v) acc[v] += w[j] * hv[j][v];
        }
    }
    for (; e < end; ++e) {
        int s = col_src[e];
        if ((unsigned)s >= (unsigned)n) s = node;
        float hv[VEC];
        loadH(s, hv);
        float w = edge_w(s);
        denom += w;
        #pragma unroll
        for (int v = 0; v < VEC; ++v) acc[v] += w * hv[v];
    }
    float inv = 1.f / (denom + 1e-16f);
    float o[VEC];
    #pragma unroll
    for (int v = 0; v < VEC; ++v) {
        o[v] = acc[v] * inv + bias[c0 + v];
        if (apply_elu) o[v] = (o[v] > 0.f) ? o[v] : (__expf(o[v]) - 1.f);
    }
    if constexpr (VEC == 4) {
        union { uint2 u; unsigned short us[4]; } cv;
        #pragma unroll
        for (int v = 0; v < 4; ++v) cv.us[v] = f2bf_bits(o[v]);
        *(uint2*)((bf16*)outp + (size_t)node * CTOT + c0) = cv.u;
    } else {
        outp[(size_t)node * CTOT + c0] = (TOUT)o[0];
    }
}

extern "C" void kernel_launch(void* const* d_in, const int* in_sizes, int n_in,
                              void* d_out, int out_size, void* d_ws, size_t ws_size,
                              hipStream_t stream) {
    const float* x   = (const float*)d_in[0];
    const int*   ei  = (const int*)d_in[1];
    const float* W0  = (const float*)d_in[2];
    const float* as0 = (const float*)d_in[3];
    const float* ad0 = (const float*)d_in[4];
    const float* b0  = (const float*)d_in[5];
    const float* W1  = (const float*)d_in[6];
    const float* as1 = (const float*)d_in[7];
    const float* ad1 = (const float*)d_in[8];
    const float* b1  = (const float*)d_in[9];
    const float* W2  = (const float*)d_in[10];
    const float* as2 = (const float*)d_in[11];
    const float* ad2 = (const float*)d_in[12];
    const float* b2  = (const float*)d_in[13];
    float* out = (float*)d_out;

    const int n = in_sizes[0] / 128;   // 50000
    const int E = in_sizes[1] / 2;     // 800000
    const int* esrc = ei;
    const int* edst = ei + E;

    // workspace (~73 MB)
    char* ws = (char*)d_ws;
    bf16* hb0 = (bf16*)ws;                                   // n*256 bf16
    bf16* hb1 = hb0 + (size_t)n * 256;                       // n*256 bf16
    bf16* xb  = hb1 + (size_t)n * 256;                       // n*128 bf16
    bf16* wt0 = xb + (size_t)n * 128;                        // 256*128
    bf16* wt1 = wt0 + 128 * 256;                             // 256*256
    bf16* wt2 = wt1 + 256 * 256;                             // 64*256
    float* asb = (float*)(wt2 + 256 * 64);                   // n*4 fp32
    float* adb = asb + (size_t)n * 4;                        // n*4 fp32 (contiguous w/ asb)
    int* row_ptr = (int*)(adb + (size_t)n * 4);              // n+1 (+pad)
    int* cursor  = row_ptr + (n + 64);                       // n  (doubles as counts)
    int* col_src = cursor + n;                               // E+n
    int* blocksums = col_src + (E + n + 64);                 // <=64

    const int nb = (n + 1023) / 1024;  // 49 scan blocks

    // ---- one-time prep: x->bf16, weight transposes, CSR ----
    convert_kernel<<<(n * 128 / 4 + 255) / 256, 256, 0, stream>>>(x, xb, n * 128 / 4);
    transpose_all_kernel<<<(114688 + 255) / 256, 256, 0, stream>>>(W0, W1, W2, wt0, wt1, wt2);
    hipMemsetAsync(cursor, 0, (size_t)n * sizeof(int), stream);
    hist_kernel<<<(E + 255) / 256, 256, 0, stream>>>(edst, cursor, E, n);
    scan_phase1<<<nb, 1024, 0, stream>>>(cursor, row_ptr, blocksums, n);
    scan_phase2<<<nb, 1024, 0, stream>>>(blocksums, row_ptr, cursor, nb, n);
    scatter_kernel<<<(E + n + 255) / 256, 256, 0, stream>>>(esrc, edst, cursor, col_src, E, n);

    dim3 blk(256);
    int mg128 = (n + 127) / 128;
    int mg64  = (n + 63) / 64;
    int ag = (n + 3) / 4;
    size_t alpha_bytes = (size_t)n * 8 * sizeof(float);  // asb+adb contiguous

    // ---- layer 0: x[n,128] @ W0[128,256] ----
    hipMemsetAsync(asb, 0, alpha_bytes, stream);
    gemm128_kernel<<<dim3(mg128, 2), blk, 0, stream>>>(xb, wt0, hb0, as0, ad0,
                                                       asb, adb, n, 128, 256, 4);
    agg_kernel<256, 4, 4, bf16><<<ag, blk, 0, stream>>>(hb0, asb, adb, row_ptr, col_src,
                                                        b0, hb1, n, 1);
    // ---- layer 1: h[n,256] @ W1[256,256] ----
    hipMemsetAsync(asb, 0, alpha_bytes, stream);
    gemm128_kernel<<<dim3(mg128, 2), blk, 0, stream>>>(hb1, wt1, hb0, as1, ad1,
                                                       asb, adb, n, 256, 256, 4);
    agg_kernel<256, 4, 4, bf16><<<ag, blk, 0, stream>>>(hb0, asb, adb, row_ptr, col_src,
                                                        b1, hb1, n, 1);
    // ---- layer 2: h[n,256] @ W2[256,64], heads=1, no ELU, fp32 out ----
    hipMemsetAsync(asb, 0, alpha_bytes, stream);
    gemm64_kernel<<<dim3(mg64, 1), blk, 0, stream>>>(hb1, wt2, hb0, as2, ad2,
                                                     asb, adb, n, 256, 64);
    agg_kernel<64, 1, 1, float><<<ag, blk, 0, stream>>>(hb0, asb, adb, row_ptr, col_src,
                                                        b2, out, n, 0);
}

// Round 9
// 476.837 us; speedup vs baseline: 2.7811x; 1.0001x over previous
//
#include <hip/hip_runtime.h>
#include <hip/hip_bf16.h>

typedef __hip_bfloat16 bf16;
typedef short s8v __attribute__((ext_vector_type(8)));   // 8 bf16 (4 VGPRs)
typedef float f32x4 __attribute__((ext_vector_type(4))); // MFMA accumulator

__device__ __forceinline__ unsigned short f2bf_bits(float x) {
    union { bf16 h; unsigned short u; } v; v.h = __float2bfloat16(x); return v.u;
}
__device__ __forceinline__ float bfbits2f(unsigned short u) {
    union { unsigned u32; float f; } v; v.u32 = ((unsigned)u) << 16; return v.f;
}

// async global->LDS, 16B per lane; LDS dest must be uniform base + lane*16
template<typename T>
__device__ __forceinline__ void gload_lds16(const T* g, T* l) {
    __builtin_amdgcn_global_load_lds(
        (const __attribute__((address_space(1))) unsigned int*)g,
        (__attribute__((address_space(3))) unsigned int*)l, 16, 0, 0);
}

__device__ __forceinline__ uint4 load8(const bf16* p) { return *(const uint4*)p; }

// ---------------- fp32 -> bf16 convert (x, one-time) ----------------
__global__ void convert_kernel(const float* __restrict__ x, bf16* __restrict__ xb, int total4) {
    int i = blockIdx.x * blockDim.x + threadIdx.x;
    if (i >= total4) return;
    float4 f = *(const float4*)(x + (size_t)i * 4);
    union { uint2 u; unsigned short us[4]; } cv;
    cv.us[0] = f2bf_bits(f.x); cv.us[1] = f2bf_bits(f.y);
    cv.us[2] = f2bf_bits(f.z); cv.us[3] = f2bf_bits(f.w);
    *(uint2*)(xb + (size_t)i * 4) = cv.u;
}

// ---------------- all 3 weight transposes in one dispatch ----------------
__device__ __forceinline__ void tr1(const float* W, bf16* Wt, int idx, int K, int N) {
    int nn = idx / K, k = idx - nn * K;
    Wt[idx] = __float2bfloat16(W[(size_t)k * N + nn]);
}
__global__ void transpose_all_kernel(const float* __restrict__ W0, const float* __restrict__ W1,
                                     const float* __restrict__ W2, bf16* __restrict__ wt0,
                                     bf16* __restrict__ wt1, bf16* __restrict__ wt2) {
    int idx = blockIdx.x * blockDim.x + threadIdx.x;
    if (idx < 32768) tr1(W0, wt0, idx, 128, 256);                       // 128x256
    else if (idx < 32768 + 65536) tr1(W1, wt1, idx - 32768, 256, 256);  // 256x256
    else if (idx < 32768 + 65536 + 16384) tr1(W2, wt2, idx - 98304, 256, 64);
}

// ---------------- CSR build ----------------
__global__ void hist_kernel(const int* __restrict__ dst, int* counts, int E, int n) {
    int i = blockIdx.x * blockDim.x + threadIdx.x;
    if (i < E) {
        int d = dst[i];
        if ((unsigned)d < (unsigned)n) atomicAdd(&counts[d], 1);
    }
}

// hierarchical scan, phase 1: per-block (1024) local exclusive scan of counts[i]+1
__global__ __launch_bounds__(1024) void scan_phase1(
        const int* __restrict__ counts, int* __restrict__ excl_out,
        int* __restrict__ blocksums, int n) {
    __shared__ int wsum[16];
    __shared__ int woff[16];
    int tid = threadIdx.x, lane = tid & 63, wid = tid >> 6;
    int i = blockIdx.x * 1024 + tid;
    int v = (i < n) ? counts[i] + 1 : 0;   // +1 = self-loop
    int incl = v;
    #pragma unroll
    for (int d = 1; d < 64; d <<= 1) {
        int t = __shfl_up(incl, d, 64);
        if (lane >= d) incl += t;
    }
    if (lane == 63) wsum[wid] = incl;
    __syncthreads();
    if (wid == 0) {
        int wv = (lane < 16) ? wsum[lane] : 0;
        int wincl = wv;
        #pragma unroll
        for (int d = 1; d < 16; d <<= 1) {
            int t = __shfl_up(wincl, d, 64);
            if (lane >= d) wincl += t;
        }
        if (lane < 16) woff[lane] = wincl - wv;
    }
    __syncthreads();
    if (i < n) excl_out[i] = woff[wid] + incl - v;
    if (tid == 1023) blocksums[blockIdx.x] = woff[15] + wsum[15];
}

// phase 2: every wave redundantly scans the <=64 block sums; apply offsets
__global__ __launch_bounds__(1024) void scan_phase2(
        const int* __restrict__ blocksums, int* __restrict__ row_ptr,
        int* __restrict__ cursor, int nb, int n) {
    int tid = threadIdx.x, lane = tid & 63;
    int i = blockIdx.x * 1024 + tid;
    int v = (lane < nb) ? blocksums[lane] : 0;
    int incl = v;
    #pragma unroll
    for (int d = 1; d < 64; d <<= 1) {
        int t = __shfl_up(incl, d, 64);
        if (lane >= d) incl += t;
    }
    int excl_lane = incl - v;
    int base = __shfl(excl_lane, blockIdx.x, 64);
    int total = __shfl(incl, nb - 1, 64);
    if (i < n) {
        int val = row_ptr[i] + base;
        row_ptr[i] = val;
        cursor[i] = val;
    }
    if (blockIdx.x == 0 && tid == 0) row_ptr[n] = total;
}

__global__ void scatter_kernel(const int* __restrict__ src, const int* __restrict__ dst,
                               int* cursor, int* col_src, int E, int n) {
    int i = blockIdx.x * blockDim.x + threadIdx.x;
    if (i < E) {
        int d = dst[i];
        if ((unsigned)d >= (unsigned)n) return;
        int s = src[i];
        if ((unsigned)s >= (unsigned)n) s = d;
        int pos = atomicAdd(&cursor[d], 1);
        col_src[pos] = s;
    } else if (i < E + n) {
        int v = i - E;
        int pos = atomicAdd(&cursor[v], 1);
        col_src[pos] = v;  // self-loop
    }
}

// ---------------- 128x128 MFMA GEMM + fused alpha epilogue ----------------
__global__ __launch_bounds__(256) void gemm128_kernel(
        const bf16* __restrict__ A, const bf16* __restrict__ Wt, bf16* __restrict__ C,
        const float* __restrict__ a_src, const float* __restrict__ a_dst,
        float* __restrict__ asb, float* __restrict__ adb,
        int M, int K, int N, int H) {
    __shared__ __align__(16) bf16 As[128 * 64];
    __shared__ __align__(16) bf16 Bs[128 * 64];
    int tid = threadIdx.x;
    int w = tid >> 6, l = tid & 63;
    int lm = l & 15, quad = l >> 4;
    int m0 = blockIdx.x * 128, n0 = blockIdx.y * 128;
    int wr = (w >> 1) * 64, wc = (w & 1) * 64;
    int srow = w * 32 + (l >> 3);
    int schunk = l & 7;
    f32x4 acc[4][4] = {};
    for (int kt = 0; kt < K; kt += 64) {
        #pragma unroll
        for (int j = 0; j < 4; ++j) {
            int row = srow + j * 8;
            int g = schunk ^ (row & 7);
            int m = m0 + row; if (m >= M) m = M - 1;  // clamp: dup rows, never stored
            gload_lds16(A + (size_t)m * K + kt + g * 8, As + row * 64 + schunk * 8);
            gload_lds16(Wt + (size_t)(n0 + row) * K + kt + g * 8, Bs + row * 64 + schunk * 8);
        }
        __syncthreads();
        #pragma unroll
        for (int ks = 0; ks < 2; ++ks) {
            s8v a[4], b[4];
            #pragma unroll
            for (int mi = 0; mi < 4; ++mi) {
                int row = wr + mi * 16 + lm;
                int c = (ks * 4 + quad) ^ (row & 7);
                a[mi] = *(const s8v*)(As + row * 64 + c * 8);
            }
            #pragma unroll
            for (int ni = 0; ni < 4; ++ni) {
                int row = wc + ni * 16 + lm;
                int c = (ks * 4 + quad) ^ (row & 7);
                b[ni] = *(const s8v*)(Bs + row * 64 + c * 8);
            }
            #pragma unroll
            for (int mi = 0; mi < 4; ++mi)
                #pragma unroll
                for (int ni = 0; ni < 4; ++ni)
                    acc[mi][ni] = __builtin_amdgcn_mfma_f32_16x16x32_bf16(
                        a[mi], b[ni], acc[mi][ni], 0, 0, 0);
        }
        __syncthreads();
    }
    int head = (n0 + wc) >> 6;
    float a_s[4], a_d[4];
    #pragma unroll
    for (int ni = 0; ni < 4; ++ni) {
        int col = n0 + wc + ni * 16 + lm;
        a_s[ni] = a_src[col];
        a_d[ni] = a_dst[col];
    }
    #pragma unroll
    for (int mi = 0; mi < 4; ++mi) {
        #pragma unroll
        for (int reg = 0; reg < 4; ++reg) {
            int m = m0 + wr + mi * 16 + quad * 4 + reg;
            float ps = 0.f, pd = 0.f;
            #pragma unroll
            for (int ni = 0; ni < 4; ++ni) {
                float v = acc[mi][ni][reg];
                ps += v * a_s[ni];
                pd += v * a_d[ni];
                if (m < M)
                    C[(size_t)m * N + n0 + wc + ni * 16 + lm] = __float2bfloat16(v);
            }
            #pragma unroll
            for (int d = 1; d < 16; d <<= 1) {
                ps += __shfl_xor(ps, d, 64);
                pd += __shfl_xor(pd, d, 64);
            }
            if (lm == 0 && m < M) {
                atomicAdd(&asb[(size_t)m * H + head], ps);
                atomicAdd(&adb[(size_t)m * H + head], pd);
            }
        }
    }
}

// ---------------- 64x64 MFMA GEMM + fused alpha (layer 2, N=64, H=1) ----------------
__global__ __launch_bounds__(256) void gemm64_kernel(
        const bf16* __restrict__ A, const bf16* __restrict__ Wt, bf16* __restrict__ C,
        const float* __restrict__ a_src, const float* __restrict__ a_dst,
        float* __restrict__ asb, float* __restrict__ adb,
        int M, int K, int N) {
    __shared__ __align__(16) bf16 As[64][72];
    __shared__ __align__(16) bf16 Bs[64][72];
    int tid = threadIdx.x;
    int m0 = blockIdx.x * 64;
    int w = tid >> 6;
    int l = tid & 63;
    int lm = l & 15;
    int quad = l >> 4;
    int r = tid >> 2;
    int kb = (tid & 3) * 8;
    f32x4 acc[4] = {};
    int mstage = m0 + r;
    for (int kt = 0; kt < K; kt += 64) {
        #pragma unroll
        for (int c = 0; c < 2; ++c) {
            int kk = kb + c * 32;
            uint4 av = (mstage < M) ? load8(&A[(size_t)mstage * K + kt + kk])
                                    : make_uint4(0, 0, 0, 0);
            *(uint4*)&As[r][kk] = av;
            *(uint4*)&Bs[r][kk] = load8(&Wt[(size_t)r * K + kt + kk]);
        }
        __syncthreads();
        #pragma unroll
        for (int ks = 0; ks < 2; ++ks) {
            s8v a = *(const s8v*)&As[w * 16 + lm][ks * 32 + quad * 8];
            #pragma unroll
            for (int nb = 0; nb < 4; ++nb) {
                s8v b = *(const s8v*)&Bs[nb * 16 + lm][ks * 32 + quad * 8];
                acc[nb] = __builtin_amdgcn_mfma_f32_16x16x32_bf16(a, b, acc[nb], 0, 0, 0);
            }
        }
        __syncthreads();
    }
    float a_s[4], a_d[4];
    #pragma unroll
    for (int nb = 0; nb < 4; ++nb) {
        a_s[nb] = a_src[nb * 16 + lm];
        a_d[nb] = a_dst[nb * 16 + lm];
    }
    #pragma unroll
    for (int reg = 0; reg < 4; ++reg) {
        int m = m0 + w * 16 + quad * 4 + reg;
        float ps = 0.f, pd = 0.f;
        #pragma unroll
        for (int nb = 0; nb < 4; ++nb) {
            float v = acc[nb][reg];
            ps += v * a_s[nb];
            pd += v * a_d[nb];
            if (m < M)
                C[(size_t)m * N + nb * 16 + lm] = __float2bfloat16(v);
        }
        #pragma unroll
        for (int d = 1; d < 16; d <<= 1) {
            ps += __shfl_xor(ps, d, 64);
            pd += __shfl_xor(pd, d, 64);
        }
        if (lm == 0 && m < M) {
            atomicAdd(&asb[m], ps);
            atomicAdd(&adb[m], pd);
        }
    }
}

// ---------------- edge-weight precompute (CSR order), node-parallel ----------------
// One wave per node; lane j handles edge slot start+j (stride 64). Computes all H
// weights once per edge (vs 16x redundant in agg) and writes them CSR-sequential.
template<int H>
__global__ __launch_bounds__(256) void wprep_kernel(
        const float* __restrict__ asb, const float* __restrict__ adb,
        const int* __restrict__ row_ptr, const int* __restrict__ col_src,
        float* __restrict__ wge, int n) {
    int lane = threadIdx.x & 63;
    int node = blockIdx.x * 4 + (threadIdx.x >> 6);
    if (node >= n) return;
    int start = row_ptr[node], end = row_ptr[node + 1];
    float adn[H];
    #pragma unroll
    for (int h = 0; h < H; ++h) adn[h] = adb[(size_t)node * H + h];
    for (int e = start + lane; e < end; e += 64) {
        int s = col_src[e];
        if ((unsigned)s >= (unsigned)n) s = node;
        #pragma unroll
        for (int h = 0; h < H; ++h) {
            float x = asb[(size_t)s * H + h] + adn[h];
            x = (x > 0.f) ? x : 0.2f * x;        // leaky_relu 0.2
            wge[(size_t)e * H + h] = __expf(fminf(x, 30.f));
        }
    }
}

// ---------------- aggregation with precomputed weights, SINGLE PASS --------
// One wave per dst node; lane owns VEC channels. 4-edge unroll for VEC=4 (8-edge
// regressed occupancy in r8), 8-edge for VEC=1 (cheap VGPRs).
template<int CTOT, int H, int VEC, typename TOUT>
__global__ __launch_bounds__(256) void agg_kernel(
        const bf16* __restrict__ hbuf, const float* __restrict__ wge,
        const int* __restrict__ row_ptr, const int* __restrict__ col_src,
        const float* __restrict__ bias,
        TOUT* __restrict__ outp, int n, int apply_elu) {
    int lane = threadIdx.x & 63;
    int node = blockIdx.x * 4 + (threadIdx.x >> 6);
    if (node >= n) return;
    const int c0 = lane * VEC;
    const int head = c0 >> 6;
    int start = row_ptr[node], end = row_ptr[node + 1];
    float acc[VEC] = {};
    float denom = 0.f;

    auto loadH = [&](int s, float* o) {
        const bf16* p = hbuf + (size_t)s * CTOT + c0;
        if constexpr (VEC == 4) {
            union { uint2 u; unsigned short us[4]; } cv;
            cv.u = *(const uint2*)p;
            #pragma unroll
            for (int v = 0; v < 4; ++v) o[v] = bfbits2f(cv.us[v]);
        } else {
            o[0] = bfbits2f(*(const unsigned short*)p);
        }
    };

    constexpr int U = (VEC == 1) ? 8 : 4;
    int e = start;
    for (; e + U <= end; e += U) {
        int s[U];
        float w[U], hv[U][VEC];
        #pragma unroll
        for (int j = 0; j < U; ++j) {
            s[j] = col_src[e + j];
            if ((unsigned)s[j] >= (unsigned)n) s[j] = node;
        }
        #pragma unroll
        for (int j = 0; j < U; ++j) w[j] = wge[(size_t)(e + j) * H + head];
        #pragma unroll
        for (int j = 0; j < U; ++j) loadH(s[j], hv[j]);
        #pragma unroll
        for (int j = 0; j < U; ++j) {
            denom += w[j];
            #pragma unroll
            for (int v = 0; v < VEC; ++v) acc[v] += w[j] * hv[j][v];
        }
    }
    for (; e < end; ++e) {
        int s = col_src[e];
        if ((unsigned)s >= (unsigned)n) s = node;
        float hv[VEC];
        loadH(s, hv);
        float w = wge[(size_t)e * H + head];
        denom += w;
        #pragma unroll
        for (int v = 0; v < VEC; ++v) acc[v] += w * hv[v];
    }
    float inv = 1.f / (denom + 1e-16f);
    float o[VEC];
    #pragma unroll
    for (int v = 0; v < VEC; ++v) {
        o[v] = acc[v] * inv + bias[c0 + v];
        if (apply_elu) o[v] = (o[v] > 0.f) ? o[v] : (__expf(o[v]) - 1.f);
    }
    if constexpr (VEC == 4) {
        union { uint2 u; unsigned short us[4]; } cv;
        #pragma unroll
        for (int v = 0; v < 4; ++v) cv.us[v] = f2bf_bits(o[v]);
        *(uint2*)((bf16*)outp + (size_t)node * CTOT + c0) = cv.u;
    } else {
        outp[(size_t)node * CTOT + c0] = (TOUT)o[0];
    }
}

extern "C" void kernel_launch(void* const* d_in, const int* in_sizes, int n_in,
                              void* d_out, int out_size, void* d_ws, size_t ws_size,
                              hipStream_t stream) {
    const float* x   = (const float*)d_in[0];
    const int*   ei  = (const int*)d_in[1];
    const float* W0  = (const float*)d_in[2];
    const float* as0 = (const float*)d_in[3];
    const float* ad0 = (const float*)d_in[4];
    const float* b0  = (const float*)d_in[5];
    const float* W1  = (const float*)d_in[6];
    const float* as1 = (const float*)d_in[7];
    const float* ad1 = (const float*)d_in[8];
    const float* b1  = (const float*)d_in[9];
    const float* W2  = (const float*)d_in[10];
    const float* as2 = (const float*)d_in[11];
    const float* ad2 = (const float*)d_in[12];
    const float* b2  = (const float*)d_in[13];
    float* out = (float*)d_out;

    const int n = in_sizes[0] / 128;   // 50000
    const int E = in_sizes[1] / 2;     // 800000
    const int* esrc = ei;
    const int* edst = ei + E;

    // workspace (~71 MB). wge aliases xb: xb consumed by layer-0 GEMM before
    // wprep (stream-ordered) overwrites the region.
    char* ws = (char*)d_ws;
    bf16* hb0 = (bf16*)ws;                                   // n*256 bf16
    bf16* hb1 = hb0 + (size_t)n * 256;                       // n*256 bf16
    bf16* xb  = hb1 + (size_t)n * 256;                       // n*128 bf16 (12.8 MB)
    float* wge = (float*)xb;                                 // (E+n)*4 fp32 (13.6 MB, alias)
    char* after_xw = (char*)xb + ((size_t)(E + n + 64) * 4 * sizeof(float));
    bf16* wt0 = (bf16*)after_xw;                             // 256*128
    bf16* wt1 = wt0 + 128 * 256;                             // 256*256
    bf16* wt2 = wt1 + 256 * 256;                             // 64*256
    float* asb = (float*)(wt2 + 256 * 64);                   // n*4 fp32
    float* adb = asb + (size_t)n * 4;                        // n*4 fp32 (contiguous w/ asb)
    int* row_ptr = (int*)(adb + (size_t)n * 4);              // n+1 (+pad)
    int* cursor  = row_ptr + (n + 64);                       // n  (doubles as counts)
    int* col_src = cursor + n;                               // E+n
    int* blocksums = col_src + (E + n + 64);                 // <=64

    const int nb = (n + 1023) / 1024;  // 49 scan blocks

    // ---- one-time prep: x->bf16, weight transposes, CSR ----
    convert_kernel<<<(n * 128 / 4 + 255) / 256, 256, 0, stream>>>(x, xb, n * 128 / 4);
    transpose_all_kernel<<<(114688 + 255) / 256, 256, 0, stream>>>(W0, W1, W2, wt0, wt1, wt2);
    hipMemsetAsync(cursor, 0, (size_t)n * sizeof(int), stream);
    hist_kernel<<<(E + 255) / 256, 256, 0, stream>>>(edst, cursor, E, n);
    scan_phase1<<<nb, 1024, 0, stream>>>(cursor, row_ptr, blocksums, n);
    scan_phase2<<<nb, 1024, 0, stream>>>(blocksums, row_ptr, cursor, nb, n);
    scatter_kernel<<<(E + n + 255) / 256, 256, 0, stream>>>(esrc, edst, cursor, col_src, E, n);

    dim3 blk(256);
    int mg128 = (n + 127) / 128;
    int mg64  = (n + 63) / 64;
    int ag = (n + 3) / 4;
    size_t alpha_bytes = (size_t)n * 8 * sizeof(float);  // asb+adb contiguous

    // ---- layer 0: x[n,128] @ W0[128,256] ----
    hipMemsetAsync(asb, 0, alpha_bytes, stream);
    gemm128_kernel<<<dim3(mg128, 2), blk, 0, stream>>>(xb, wt0, hb0, as0, ad0,
                                                       asb, adb, n, 128, 256, 4);
    wprep_kernel<4><<<ag, blk, 0, stream>>>(asb, adb, row_ptr, col_src, wge, n);
    agg_kernel<256, 4, 4, bf16><<<ag, blk, 0, stream>>>(hb0, wge, row_ptr, col_src,
                                                        b0, hb1, n, 1);
    // ---- layer 1: h[n,256] @ W1[256,256] ----
    hipMemsetAsync(asb, 0, alpha_bytes, stream);
    gemm128_kernel<<<dim3(mg128, 2), blk, 0, stream>>>(hb1, wt1, hb0, as1, ad1,
                                                       asb, adb, n, 256, 256, 4);
    wprep_kernel<4><<<ag, blk, 0, stream>>>(asb, adb, row_ptr, col_src, wge, n);
    agg_kernel<256, 4, 4, bf16><<<ag, blk, 0, stream>>>(hb0, wge, row_ptr, col_src,
                                                        b1, hb1, n, 1);
    // ---- layer 2: h[n,256] @ W2[256,64], heads=1, no ELU, fp32 out ----
    hipMemsetAsync(asb, 0, alpha_bytes, stream);
    gemm64_kernel<<<dim3(mg64, 1), blk, 0, stream>>>(hb1, wt2, hb0, as2, ad2,
                                                     asb, adb, n, 256, 64);
    wprep_kernel<1><<<ag, blk, 0, stream>>>(asb, adb, row_ptr, col_src, wge, n);
    agg_kernel<64, 1, 1, float><<<ag, blk, 0, stream>>>(hb0, wge, row_ptr, col_src,
                                                        b2, out, n, 0);
}

// Round 10
// 428.998 us; speedup vs baseline: 3.0912x; 1.1115x over previous
//
#include <hip/hip_runtime.h>
#include <hip/hip_bf16.h>

typedef __hip_bfloat16 bf16;
typedef short s8v __attribute__((ext_vector_type(8)));   // 8 bf16 (4 VGPRs)
typedef float f32x4 __attribute__((ext_vector_type(4))); // MFMA accumulator

__device__ __forceinline__ unsigned short f2bf_bits(float x) {
    union { bf16 h; unsigned short u; } v; v.h = __float2bfloat16(x); return v.u;
}
__device__ __forceinline__ float bfbits2f(unsigned short u) {
    union { unsigned u32; float f; } v; v.u32 = ((unsigned)u) << 16; return v.f;
}

// async global->LDS, 16B per lane; LDS dest must be uniform base + lane*16
template<typename T>
__device__ __forceinline__ void gload_lds16(const T* g, T* l) {
    __builtin_amdgcn_global_load_lds(
        (const __attribute__((address_space(1))) unsigned int*)g,
        (__attribute__((address_space(3))) unsigned int*)l, 16, 0, 0);
}

__device__ __forceinline__ uint4 load8(const bf16* p) { return *(const uint4*)p; }

// ---------------- mega-prep: x->bf16 + 3 weight transposes + zero cursor ----------------
__device__ __forceinline__ void tr1(const float* W, bf16* Wt, int idx, int K, int N) {
    int nn = idx / K, k = idx - nn * K;
    Wt[idx] = __float2bfloat16(W[(size_t)k * N + nn]);
}
__global__ void prep_kernel(const float* __restrict__ x, bf16* __restrict__ xb, int nc4,
                            const float* __restrict__ W0, const float* __restrict__ W1,
                            const float* __restrict__ W2, bf16* __restrict__ wt0,
                            bf16* __restrict__ wt1, bf16* __restrict__ wt2,
                            int* __restrict__ cursor, int n) {
    int idx = blockIdx.x * blockDim.x + threadIdx.x;
    if (idx < nc4) {
        float4 f = *(const float4*)(x + (size_t)idx * 4);
        union { uint2 u; unsigned short us[4]; } cv;
        cv.us[0] = f2bf_bits(f.x); cv.us[1] = f2bf_bits(f.y);
        cv.us[2] = f2bf_bits(f.z); cv.us[3] = f2bf_bits(f.w);
        *(uint2*)(xb + (size_t)idx * 4) = cv.u;
        return;
    }
    int i2 = idx - nc4;
    if (i2 < 32768) { tr1(W0, wt0, i2, 128, 256); return; }
    i2 -= 32768;
    if (i2 < 65536) { tr1(W1, wt1, i2, 256, 256); return; }
    i2 -= 65536;
    if (i2 < 16384) { tr1(W2, wt2, i2, 256, 64); return; }
    i2 -= 16384;
    if (i2 < n) cursor[i2] = 0;
}

// ---------------- CSR build ----------------
__global__ void hist_kernel(const int* __restrict__ dst, int* counts, int E, int n) {
    int i = blockIdx.x * blockDim.x + threadIdx.x;
    if (i < E) {
        int d = dst[i];
        if ((unsigned)d < (unsigned)n) atomicAdd(&counts[d], 1);
    }
}

// hierarchical scan, phase 1: per-block (1024) local exclusive scan of counts[i]+1
__global__ __launch_bounds__(1024) void scan_phase1(
        const int* __restrict__ counts, int* __restrict__ excl_out,
        int* __restrict__ blocksums, int n) {
    __shared__ int wsum[16];
    __shared__ int woff[16];
    int tid = threadIdx.x, lane = tid & 63, wid = tid >> 6;
    int i = blockIdx.x * 1024 + tid;
    int v = (i < n) ? counts[i] + 1 : 0;   // +1 = self-loop
    int incl = v;
    #pragma unroll
    for (int d = 1; d < 64; d <<= 1) {
        int t = __shfl_up(incl, d, 64);
        if (lane >= d) incl += t;
    }
    if (lane == 63) wsum[wid] = incl;
    __syncthreads();
    if (wid == 0) {
        int wv = (lane < 16) ? wsum[lane] : 0;
        int wincl = wv;
        #pragma unroll
        for (int d = 1; d < 16; d <<= 1) {
            int t = __shfl_up(wincl, d, 64);
            if (lane >= d) wincl += t;
        }
        if (lane < 16) woff[lane] = wincl - wv;
    }
    __syncthreads();
    if (i < n) excl_out[i] = woff[wid] + incl - v;
    if (tid == 1023) blocksums[blockIdx.x] = woff[15] + wsum[15];
}

// phase 2: every wave redundantly scans the <=64 block sums; apply offsets
__global__ __launch_bounds__(1024) void scan_phase2(
        const int* __restrict__ blocksums, int* __restrict__ row_ptr,
        int* __restrict__ cursor, int nb, int n) {
    int tid = threadIdx.x, lane = tid & 63;
    int i = blockIdx.x * 1024 + tid;
    int v = (lane < nb) ? blocksums[lane] : 0;
    int incl = v;
    #pragma unroll
    for (int d = 1; d < 64; d <<= 1) {
        int t = __shfl_up(incl, d, 64);
        if (lane >= d) incl += t;
    }
    int excl_lane = incl - v;
    int base = __shfl(excl_lane, blockIdx.x, 64);
    int total = __shfl(incl, nb - 1, 64);
    if (i < n) {
        int val = row_ptr[i] + base;
        row_ptr[i] = val;
        cursor[i] = val;
    }
    if (blockIdx.x == 0 && tid == 0) row_ptr[n] = total;
}

__global__ void scatter_kernel(const int* __restrict__ src, const int* __restrict__ dst,
                               int* cursor, int* col_src, int E, int n) {
    int i = blockIdx.x * blockDim.x + threadIdx.x;
    if (i < E) {
        int d = dst[i];
        if ((unsigned)d >= (unsigned)n) return;
        int s = src[i];
        if ((unsigned)s >= (unsigned)n) s = d;
        int pos = atomicAdd(&cursor[d], 1);
        col_src[pos] = s;
    } else if (i < E + n) {
        int v = i - E;
        int pos = atomicAdd(&cursor[v], 1);
        col_src[pos] = v;  // self-loop
    }
}

// ---------------- 128x128 MFMA GEMM + fused alpha epilogue (direct store) ----------------
// Each (m, head) partial is produced by exactly ONE wave of ONE block: wave's 64-col
// span == one head, m-ranges disjoint across blocks -> plain store, no memset needed.
__global__ __launch_bounds__(256) void gemm128_kernel(
        const bf16* __restrict__ A, const bf16* __restrict__ Wt, bf16* __restrict__ C,
        const float* __restrict__ a_src, const float* __restrict__ a_dst,
        float* __restrict__ asb, float* __restrict__ adb,
        int M, int K, int N, int H) {
    __shared__ __align__(16) bf16 As[128 * 64];
    __shared__ __align__(16) bf16 Bs[128 * 64];
    int tid = threadIdx.x;
    int w = tid >> 6, l = tid & 63;
    int lm = l & 15, quad = l >> 4;
    int m0 = blockIdx.x * 128, n0 = blockIdx.y * 128;
    int wr = (w >> 1) * 64, wc = (w & 1) * 64;
    int srow = w * 32 + (l >> 3);
    int schunk = l & 7;
    f32x4 acc[4][4] = {};
    for (int kt = 0; kt < K; kt += 64) {
        #pragma unroll
        for (int j = 0; j < 4; ++j) {
            int row = srow + j * 8;
            int g = schunk ^ (row & 7);
            int m = m0 + row; if (m >= M) m = M - 1;  // clamp: dup rows, never stored
            gload_lds16(A + (size_t)m * K + kt + g * 8, As + row * 64 + schunk * 8);
            gload_lds16(Wt + (size_t)(n0 + row) * K + kt + g * 8, Bs + row * 64 + schunk * 8);
        }
        __syncthreads();
        #pragma unroll
        for (int ks = 0; ks < 2; ++ks) {
            s8v a[4], b[4];
            #pragma unroll
            for (int mi = 0; mi < 4; ++mi) {
                int row = wr + mi * 16 + lm;
                int c = (ks * 4 + quad) ^ (row & 7);
                a[mi] = *(const s8v*)(As + row * 64 + c * 8);
            }
            #pragma unroll
            for (int ni = 0; ni < 4; ++ni) {
                int row = wc + ni * 16 + lm;
                int c = (ks * 4 + quad) ^ (row & 7);
                b[ni] = *(const s8v*)(Bs + row * 64 + c * 8);
            }
            #pragma unroll
            for (int mi = 0; mi < 4; ++mi)
                #pragma unroll
                for (int ni = 0; ni < 4; ++ni)
                    acc[mi][ni] = __builtin_amdgcn_mfma_f32_16x16x32_bf16(
                        a[mi], b[ni], acc[mi][ni], 0, 0, 0);
        }
        __syncthreads();
    }
    int head = (n0 + wc) >> 6;
    float a_s[4], a_d[4];
    #pragma unroll
    for (int ni = 0; ni < 4; ++ni) {
        int col = n0 + wc + ni * 16 + lm;
        a_s[ni] = a_src[col];
        a_d[ni] = a_dst[col];
    }
    #pragma unroll
    for (int mi = 0; mi < 4; ++mi) {
        #pragma unroll
        for (int reg = 0; reg < 4; ++reg) {
            int m = m0 + wr + mi * 16 + quad * 4 + reg;
            float ps = 0.f, pd = 0.f;
            #pragma unroll
            for (int ni = 0; ni < 4; ++ni) {
                float v = acc[mi][ni][reg];
                ps += v * a_s[ni];
                pd += v * a_d[ni];
                if (m < M)
                    C[(size_t)m * N + n0 + wc + ni * 16 + lm] = __float2bfloat16(v);
            }
            #pragma unroll
            for (int d = 1; d < 16; d <<= 1) {
                ps += __shfl_xor(ps, d, 64);
                pd += __shfl_xor(pd, d, 64);
            }
            if (lm == 0 && m < M) {
                asb[(size_t)m * H + head] = ps;
                adb[(size_t)m * H + head] = pd;
            }
        }
    }
}

// ---------------- 64x64 MFMA GEMM + fused alpha (layer 2, N=64, H=1, direct store) ----
__global__ __launch_bounds__(256) void gemm64_kernel(
        const bf16* __restrict__ A, const bf16* __restrict__ Wt, bf16* __restrict__ C,
        const float* __restrict__ a_src, const float* __restrict__ a_dst,
        float* __restrict__ asb, float* __restrict__ adb,
        int M, int K, int N) {
    __shared__ __align__(16) bf16 As[64][72];
    __shared__ __align__(16) bf16 Bs[64][72];
    int tid = threadIdx.x;
    int m0 = blockIdx.x * 64;
    int w = tid >> 6;
    int l = tid & 63;
    int lm = l & 15;
    int quad = l >> 4;
    int r = tid >> 2;
    int kb = (tid & 3) * 8;
    f32x4 acc[4] = {};
    int mstage = m0 + r;
    for (int kt = 0; kt < K; kt += 64) {
        #pragma unroll
        for (int c = 0; c < 2; ++c) {
            int kk = kb + c * 32;
            uint4 av = (mstage < M) ? load8(&A[(size_t)mstage * K + kt + kk])
                                    : make_uint4(0, 0, 0, 0);
            *(uint4*)&As[r][kk] = av;
            *(uint4*)&Bs[r][kk] = load8(&Wt[(size_t)r * K + kt + kk]);
        }
        __syncthreads();
        #pragma unroll
        for (int ks = 0; ks < 2; ++ks) {
            s8v a = *(const s8v*)&As[w * 16 + lm][ks * 32 + quad * 8];
            #pragma unroll
            for (int nb = 0; nb < 4; ++nb) {
                s8v b = *(const s8v*)&Bs[nb * 16 + lm][ks * 32 + quad * 8];
                acc[nb] = __builtin_amdgcn_mfma_f32_16x16x32_bf16(a, b, acc[nb], 0, 0, 0);
            }
        }
        __syncthreads();
    }
    float a_s[4], a_d[4];
    #pragma unroll
    for (int nb = 0; nb < 4; ++nb) {
        a_s[nb] = a_src[nb * 16 + lm];
        a_d[nb] = a_dst[nb * 16 + lm];
    }
    #pragma unroll
    for (int reg = 0; reg < 4; ++reg) {
        int m = m0 + w * 16 + quad * 4 + reg;
        float ps = 0.f, pd = 0.f;
        #pragma unroll
        for (int nb = 0; nb < 4; ++nb) {
            float v = acc[nb][reg];
            ps += v * a_s[nb];
            pd += v * a_d[nb];
            if (m < M)
                C[(size_t)m * N + nb * 16 + lm] = __float2bfloat16(v);
        }
        #pragma unroll
        for (int d = 1; d < 16; d <<= 1) {
            ps += __shfl_xor(ps, d, 64);
            pd += __shfl_xor(pd, d, 64);
        }
        if (lm == 0 && m < M) {
            asb[m] = ps;
            adb[m] = pd;
        }
    }
}

// ---------------- fused edge-softmax + aggregation, SINGLE PASS ----------------
// One wave per dst node; lane owns VEC channels. Edge weights computed in-wave
// with NO redundancy: per BATCH=64/H edges, lane (head, slot) computes one
// (edge, head) weight; __shfl broadcasts to the lanes of that head. Bit-identical
// fp32 math vs the separate wprep kernel.
template<int CTOT, int H, int VEC, typename TOUT>
__global__ __launch_bounds__(256) void agg_kernel(
        const bf16* __restrict__ hbuf,
        const float* __restrict__ asb, const float* __restrict__ adb,
        const int* __restrict__ row_ptr, const int* __restrict__ col_src,
        const float* __restrict__ bias,
        TOUT* __restrict__ outp, int n, int apply_elu) {
    constexpr int BATCH = 64 / H;
    int lane = threadIdx.x & 63;
    int node = blockIdx.x * 4 + (threadIdx.x >> 6);
    if (node >= n) return;
    const int c0 = lane * VEC;
    const int head = lane / BATCH;     // == c0>>6
    const int sub = lane % BATCH;
    int start = row_ptr[node], end = row_ptr[node + 1];
    float adn = adb[(size_t)node * H + head];
    float acc[VEC] = {};
    float denom = 0.f;

    auto loadH = [&](int s, float* o) {
        const bf16* p = hbuf + (size_t)s * CTOT + c0;
        if constexpr (VEC == 4) {
            union { uint2 u; unsigned short us[4]; } cv;
            cv.u = *(const uint2*)p;
            #pragma unroll
            for (int v = 0; v < 4; ++v) o[v] = bfbits2f(cv.us[v]);
        } else {
            o[0] = bfbits2f(*(const unsigned short*)p);
        }
    };

    for (int base = start; base < end; base += BATCH) {
        int nbatch = end - base;
        if (nbatch > BATCH) nbatch = BATCH;
        // phase A: lane (head, sub) computes w for edge base+sub at its head
        float wv = 0.f;
        if (sub < nbatch) {
            int s = col_src[base + sub];
            float xv = asb[(size_t)s * H + head] + adn;
            xv = (xv > 0.f) ? xv : 0.2f * xv;      // leaky_relu 0.2
            wv = __expf(fminf(xv, 30.f));
        }
        // phase B: accumulate, 4-edge groups (proven ILP shape from r9)
        int j = 0;
        for (; j + 4 <= nbatch; j += 4) {
            int s0 = col_src[base + j], s1 = col_src[base + j + 1];
            int s2 = col_src[base + j + 2], s3 = col_src[base + j + 3];
            float hv0[VEC], hv1[VEC], hv2[VEC], hv3[VEC];
            loadH(s0, hv0); loadH(s1, hv1); loadH(s2, hv2); loadH(s3, hv3);
            float w0 = __shfl(wv, head * BATCH + j, 64);
            float w1 = __shfl(wv, head * BATCH + j + 1, 64);
            float w2 = __shfl(wv, head * BATCH + j + 2, 64);
            float w3 = __shfl(wv, head * BATCH + j + 3, 64);
            denom += (w0 + w1) + (w2 + w3);
            #pragma unroll
            for (int v = 0; v < VEC; ++v)
                acc[v] += w0 * hv0[v] + w1 * hv1[v] + w2 * hv2[v] + w3 * hv3[v];
        }
        for (; j < nbatch; ++j) {
            int s = col_src[base + j];
            float hv[VEC];
            loadH(s, hv);
            float wj = __shfl(wv, head * BATCH + j, 64);
            denom += wj;
            #pragma unroll
            for (int v = 0; v < VEC; ++v) acc[v] += wj * hv[v];
        }
    }
    float inv = 1.f / (denom + 1e-16f);
    float o[VEC];
    #pragma unroll
    for (int v = 0; v < VEC; ++v) {
        o[v] = acc[v] * inv + bias[c0 + v];
        if (apply_elu) o[v] = (o[v] > 0.f) ? o[v] : (__expf(o[v]) - 1.f);
    }
    if constexpr (VEC == 4) {
        union { uint2 u; unsigned short us[4]; } cv;
        #pragma unroll
        for (int v = 0; v < 4; ++v) cv.us[v] = f2bf_bits(o[v]);
        *(uint2*)((bf16*)outp + (size_t)node * CTOT + c0) = cv.u;
    } else {
        outp[(size_t)node * CTOT + c0] = (TOUT)o[0];
    }
}

extern "C" void kernel_launch(void* const* d_in, const int* in_sizes, int n_in,
                              void* d_out, int out_size, void* d_ws, size_t ws_size,
                              hipStream_t stream) {
    const float* x   = (const float*)d_in[0];
    const int*   ei  = (const int*)d_in[1];
    const float* W0  = (const float*)d_in[2];
    const float* as0 = (const float*)d_in[3];
    const float* ad0 = (const float*)d_in[4];
    const float* b0  = (const float*)d_in[5];
    const float* W1  = (const float*)d_in[6];
    const float* as1 = (const float*)d_in[7];
    const float* ad1 = (const float*)d_in[8];
    const float* b1  = (const float*)d_in[9];
    const float* W2  = (const float*)d_in[10];
    const float* as2 = (const float*)d_in[11];
    const float* ad2 = (const float*)d_in[12];
    const float* b2  = (const float*)d_in[13];
    float* out = (float*)d_out;

    const int n = in_sizes[0] / 128;   // 50000
    const int E = in_sizes[1] / 2;     // 800000
    const int* esrc = ei;
    const int* edst = ei + E;

    // workspace (~58 MB)
    char* ws = (char*)d_ws;
    bf16* hb0 = (bf16*)ws;                                   // n*256 bf16
    bf16* hb1 = hb0 + (size_t)n * 256;                       // n*256 bf16
    bf16* xb  = hb1 + (size_t)n * 256;                       // n*128 bf16
    bf16* wt0 = xb + (size_t)n * 128;                        // 256*128
    bf16* wt1 = wt0 + 128 * 256;                             // 256*256
    bf16* wt2 = wt1 + 256 * 256;                             // 64*256
    float* asb = (float*)(wt2 + 256 * 64);                   // n*4 fp32
    float* adb = asb + (size_t)n * 4;                        // n*4 fp32
    int* row_ptr = (int*)(adb + (size_t)n * 4);              // n+1 (+pad)
    int* cursor  = row_ptr + (n + 64);                       // n  (doubles as counts)
    int* col_src = cursor + n;                               // E+n
    int* blocksums = col_src + (E + n + 64);                 // <=64

    const int nb = (n + 1023) / 1024;  // 49 scan blocks
    const int nc4 = n * 128 / 4;       // x convert quads

    // ---- one-time prep (1 dispatch) + CSR build (4 dispatches) ----
    int prep_threads = nc4 + 114688 + n;
    prep_kernel<<<(prep_threads + 255) / 256, 256, 0, stream>>>(
        x, xb, nc4, W0, W1, W2, wt0, wt1, wt2, cursor, n);
    hist_kernel<<<(E + 255) / 256, 256, 0, stream>>>(edst, cursor, E, n);
    scan_phase1<<<nb, 1024, 0, stream>>>(cursor, row_ptr, blocksums, n);
    scan_phase2<<<nb, 1024, 0, stream>>>(blocksums, row_ptr, cursor, nb, n);
    scatter_kernel<<<(E + n + 255) / 256, 256, 0, stream>>>(esrc, edst, cursor, col_src, E, n);

    dim3 blk(256);
    int mg128 = (n + 127) / 128;
    int mg64  = (n + 63) / 64;
    int ag = (n + 3) / 4;

    // ---- layer 0: x[n,128] @ W0[128,256] ----
    gemm128_kernel<<<dim3(mg128, 2), blk, 0, stream>>>(xb, wt0, hb0, as0, ad0,
                                                       asb, adb, n, 128, 256, 4);
    agg_kernel<256, 4, 4, bf16><<<ag, blk, 0, stream>>>(hb0, asb, adb, row_ptr, col_src,
                                                        b0, hb1, n, 1);
    // ---- layer 1: h[n,256] @ W1[256,256] ----
    gemm128_kernel<<<dim3(mg128, 2), blk, 0, stream>>>(hb1, wt1, hb0, as1, ad1,
                                                       asb, adb, n, 256, 256, 4);
    agg_kernel<256, 4, 4, bf16><<<ag, blk, 0, stream>>>(hb0, asb, adb, row_ptr, col_src,
                                                        b1, hb1, n, 1);
    // ---- layer 2: h[n,256] @ W2[256,64], heads=1, no ELU, fp32 out ----
    gemm64_kernel<<<dim3(mg64, 1), blk, 0, stream>>>(hb1, wt2, hb0, as2, ad2,
                                                     asb, adb, n, 256, 64);
    agg_kernel<64, 1, 1, float><<<ag, blk, 0, stream>>>(hb0, asb, adb, row_ptr, col_src,
                                                        b2, out, n, 0);
}